// Round 1
// baseline (3019.842 us; speedup 1.0000x reference)
//
#include <hip/hip_runtime.h>

#define NN 50000
#define CC 128
#define OC 64
#define EE 800000

// ---------------- degree ----------------
__global__ void k_deg(const int* __restrict__ dst, float* __restrict__ deg) {
    int e = blockIdx.x * blockDim.x + threadIdx.x;
    if (e < EE) atomicAdd(&deg[dst[e]], 1.0f);
}

__global__ void k_deginv(float* __restrict__ deg) {
    int i = blockIdx.x * blockDim.x + threadIdx.x;
    if (i < NN) deg[i] = 1.0f / fmaxf(deg[i], 1.0f);
}

// ---------------- scatter-add: aggr[dst] += x[src] ----------------
// 32 lanes per edge, float4 per lane (32*16B = 512B = one 128-f32 row)
__global__ void k_scatter(const int* __restrict__ src, const int* __restrict__ dst,
                          const float* __restrict__ x, float* __restrict__ aggr) {
    long long gid = (long long)blockIdx.x * blockDim.x + threadIdx.x;
    int e = (int)(gid >> 5);
    int lane = (int)(gid & 31);
    if (e >= EE) return;
    int s = src[e], d = dst[e];
    float4 v = ((const float4*)(x + (long long)s * CC))[lane];
    float* out = aggr + (long long)d * CC + lane * 4;
    atomicAdd(out + 0, v.x);
    atomicAdd(out + 1, v.y);
    atomicAdd(out + 2, v.z);
    atomicAdd(out + 3, v.w);
}

// ---------------- fused SAGE layer ----------------
// out[row] = relu( (aggr[row]*deginv[row]) @ Wl + b + x[row] @ Wr )
// block = 256 threads, 64 rows/block. Each thread: 8 rows x 4 cols.
__global__ __launch_bounds__(256) void k_layer(
    const float* __restrict__ aggr, const float* __restrict__ xin,
    const float* __restrict__ deginv,
    const float* __restrict__ Wl, const float* __restrict__ bias,
    const float* __restrict__ Wr, float* __restrict__ out) {
    __shared__ float a_sh[64][CC];
    __shared__ float x_sh[64][CC];
    int row0 = blockIdx.x * 64;
    int tid = threadIdx.x;
    // stage 64 rows of scaled-aggr and x: 2048 float4s, 8 per thread
    for (int i = tid; i < 64 * CC / 4; i += 256) {
        int r = i >> 5;       // i / 32
        int c4 = i & 31;      // i % 32
        int row = row0 + r;
        float4 av = make_float4(0.f, 0.f, 0.f, 0.f);
        float4 xv = make_float4(0.f, 0.f, 0.f, 0.f);
        if (row < NN) {
            float di = deginv[row];
            av = ((const float4*)(aggr + (long long)row * CC))[c4];
            av.x *= di; av.y *= di; av.z *= di; av.w *= di;
            xv = ((const float4*)(xin + (long long)row * CC))[c4];
        }
        ((float4*)a_sh[r])[c4] = av;
        ((float4*)x_sh[r])[c4] = xv;
    }
    __syncthreads();

    int col = (tid & 31) * 4;   // 32 col-groups x 4 cols = 128 cols
    int rg  = tid >> 5;         // 8 row-groups x 8 rows = 64 rows
    float4 bv = *(const float4*)(bias + col);
    float acc[8][4];
#pragma unroll
    for (int r = 0; r < 8; ++r) {
        acc[r][0] = bv.x; acc[r][1] = bv.y; acc[r][2] = bv.z; acc[r][3] = bv.w;
    }
    for (int k = 0; k < CC; ++k) {
        float4 wl = *(const float4*)(Wl + k * CC + col);
        float4 wr = *(const float4*)(Wr + k * CC + col);
#pragma unroll
        for (int r = 0; r < 8; ++r) {
            float a  = a_sh[rg * 8 + r][k];
            float xx = x_sh[rg * 8 + r][k];
            acc[r][0] += a * wl.x + xx * wr.x;
            acc[r][1] += a * wl.y + xx * wr.y;
            acc[r][2] += a * wl.z + xx * wr.z;
            acc[r][3] += a * wl.w + xx * wr.w;
        }
    }
#pragma unroll
    for (int r = 0; r < 8; ++r) {
        int row = row0 + rg * 8 + r;
        if (row < NN) {
            float4 o;
            o.x = fmaxf(acc[r][0], 0.f);
            o.y = fmaxf(acc[r][1], 0.f);
            o.z = fmaxf(acc[r][2], 0.f);
            o.w = fmaxf(acc[r][3], 0.f);
            *(float4*)(out + (long long)row * CC + col) = o;
        }
    }
}

// ---------------- classifier: logits = h @ Wc + bc ----------------
// block = 256 threads = 16 rows x (16 col-groups x 4 cols = 64 cols)
__global__ __launch_bounds__(256) void k_cls(
    const float* __restrict__ h, const float* __restrict__ Wc,
    const float* __restrict__ bc, float* __restrict__ logits) {
    __shared__ float h_sh[16][CC];
    int row0 = blockIdx.x * 16;
    int tid = threadIdx.x;
    for (int i = tid; i < 16 * CC / 4; i += 256) {  // 512 float4s
        int r = i >> 5, c4 = i & 31;
        int row = row0 + r;
        float4 v = make_float4(0.f, 0.f, 0.f, 0.f);
        if (row < NN) v = ((const float4*)(h + (long long)row * CC))[c4];
        ((float4*)h_sh[r])[c4] = v;
    }
    __syncthreads();
    int col = (tid & 15) * 4;
    int r = tid >> 4;  // 0..15
    float4 bv = *(const float4*)(bc + col);
    float a0 = bv.x, a1 = bv.y, a2 = bv.z, a3 = bv.w;
    for (int k = 0; k < CC; ++k) {
        float hv = h_sh[r][k];
        float4 w = *(const float4*)(Wc + k * OC + col);
        a0 += hv * w.x; a1 += hv * w.y; a2 += hv * w.z; a3 += hv * w.w;
    }
    int row = row0 + r;
    if (row < NN) {
        float4 o = make_float4(a0, a1, a2, a3);
        *(float4*)(logits + (long long)row * OC + col) = o;
    }
}

extern "C" void kernel_launch(void* const* d_in, const int* in_sizes, int n_in,
                              void* d_out, int out_size, void* d_ws, size_t ws_size,
                              hipStream_t stream) {
    const float* x_doc = (const float*)d_in[0];
    // d_in[1] = x_token (unused by reference)
    const int* ei = (const int*)d_in[2];
    // d_in[3] = edge_weight (unused by reference)
    const float* W1l = (const float*)d_in[4];
    const float* b1  = (const float*)d_in[5];
    const float* W1r = (const float*)d_in[6];
    const float* W2l = (const float*)d_in[7];
    const float* b2  = (const float*)d_in[8];
    const float* W2r = (const float*)d_in[9];
    const float* Wc  = (const float*)d_in[10];
    const float* bc  = (const float*)d_in[11];

    const int* src = ei;        // edge_index[0]
    const int* dst = ei + EE;   // edge_index[1]

    float* deg  = (float*)d_ws;                    // NN floats (deg -> deg_inv in place)
    float* aggr = deg + 51200;                     // NN*CC floats
    float* h1   = aggr + (long long)NN * CC;       // NN*CC floats

    float* logits = (float*)d_out;                 // NN*OC
    float* h2     = logits + (long long)NN * OC;   // NN*CC (second tuple output)

    hipMemsetAsync(deg, 0, NN * sizeof(float), stream);
    hipMemsetAsync(aggr, 0, (size_t)NN * CC * sizeof(float), stream);

    k_deg<<<(EE + 255) / 256, 256, 0, stream>>>(dst, deg);
    k_deginv<<<(NN + 255) / 256, 256, 0, stream>>>(deg);

    // layer 1
    k_scatter<<<(EE * 32) / 256, 256, 0, stream>>>(src, dst, x_doc, aggr);
    k_layer<<<(NN + 63) / 64, 256, 0, stream>>>(aggr, x_doc, deg, W1l, b1, W1r, h1);

    // layer 2
    hipMemsetAsync(aggr, 0, (size_t)NN * CC * sizeof(float), stream);
    k_scatter<<<(EE * 32) / 256, 256, 0, stream>>>(src, dst, h1, aggr);
    k_layer<<<(NN + 63) / 64, 256, 0, stream>>>(aggr, h1, deg, W2l, b2, W2r, h2);

    // classifier
    k_cls<<<(NN + 15) / 16, 256, 0, stream>>>(h2, Wc, bc, logits);
}

// Round 2
// 478.360 us; speedup vs baseline: 6.3129x; 6.3129x over previous
//
#include <hip/hip_runtime.h>

#define NN 50000
#define CC 128
#define OC 64
#define EE 800000
#define NB 196  // ceil(NN/256)

// ---------------- CSR build: count, scan, place ----------------
__global__ void k_count(const int* __restrict__ dst, int* __restrict__ ideg) {
    int e = blockIdx.x * blockDim.x + threadIdx.x;
    if (e < EE) atomicAdd(&ideg[dst[e]], 1);
}

__global__ __launch_bounds__(256) void k_scan1(const int* __restrict__ ideg,
                                               int* __restrict__ partials) {
    __shared__ int sh[256];
    int idx = blockIdx.x * 256 + threadIdx.x;
    sh[threadIdx.x] = (idx < NN) ? ideg[idx] : 0;
    __syncthreads();
    for (int s = 128; s > 0; s >>= 1) {
        if (threadIdx.x < s) sh[threadIdx.x] += sh[threadIdx.x + s];
        __syncthreads();
    }
    if (threadIdx.x == 0) partials[blockIdx.x] = sh[0];
}

__global__ void k_scan2(int* __restrict__ partials) {
    if (threadIdx.x == 0 && blockIdx.x == 0) {
        int acc = 0;
        for (int i = 0; i < NB; ++i) { int v = partials[i]; partials[i] = acc; acc += v; }
    }
}

__global__ __launch_bounds__(256) void k_scan3(const int* __restrict__ ideg,
                                               const int* __restrict__ partials,
                                               int* __restrict__ off, int* __restrict__ cursor) {
    __shared__ int sh[256];
    int idx = blockIdx.x * 256 + threadIdx.x;
    int v = (idx < NN) ? ideg[idx] : 0;
    sh[threadIdx.x] = v;
    __syncthreads();
    for (int d = 1; d < 256; d <<= 1) {   // Hillis-Steele inclusive scan
        int t = (threadIdx.x >= d) ? sh[threadIdx.x - d] : 0;
        __syncthreads();
        sh[threadIdx.x] += t;
        __syncthreads();
    }
    int excl = sh[threadIdx.x] - v + partials[blockIdx.x];
    if (idx < NN) { off[idx] = excl; cursor[idx] = excl; }
    if (idx == NN - 1) off[NN] = excl + v;   // == EE
}

__global__ void k_place(const int* __restrict__ src, const int* __restrict__ dst,
                        int* __restrict__ cursor, int* __restrict__ ssrc) {
    int e = blockIdx.x * blockDim.x + threadIdx.x;
    if (e < EE) {
        int p = atomicAdd(&cursor[dst[e]], 1);
        ssrc[p] = src[e];
    }
}

// ---------------- gather: aggr[i] = mean_{j in N(i)} x[src_j] ----------------
// one wave (64 lanes) per dst node; lane holds float2 (cols 2*lane, 2*lane+1)
__global__ __launch_bounds__(256) void k_gather(const int* __restrict__ off,
                                                const int* __restrict__ ssrc,
                                                const float* __restrict__ x,
                                                float* __restrict__ aggr) {
    int wid = blockIdx.x * 4 + (threadIdx.x >> 6);
    int lane = threadIdx.x & 63;
    if (wid >= NN) return;
    int s0 = off[wid], s1 = off[wid + 1];
    float ax = 0.f, ay = 0.f;
    int j = s0;
    for (; j + 1 < s1; j += 2) {           // 2-deep MLP
        int sa = ssrc[j], sb = ssrc[j + 1];
        float2 va = ((const float2*)(x + (long long)sa * CC))[lane];
        float2 vb = ((const float2*)(x + (long long)sb * CC))[lane];
        ax += va.x + vb.x; ay += va.y + vb.y;
    }
    if (j < s1) {
        int sa = ssrc[j];
        float2 va = ((const float2*)(x + (long long)sa * CC))[lane];
        ax += va.x; ay += va.y;
    }
    float dinv = 1.0f / fmaxf((float)(s1 - s0), 1.0f);
    float2 o = make_float2(ax * dinv, ay * dinv);
    ((float2*)(aggr + (long long)wid * CC))[lane] = o;
}

// ---------------- fused SAGE layer ----------------
// out[row] = relu( aggr[row] @ Wl + b + x[row] @ Wr )   (aggr already mean-scaled)
__global__ __launch_bounds__(256) void k_layer(
    const float* __restrict__ aggr, const float* __restrict__ xin,
    const float* __restrict__ Wl, const float* __restrict__ bias,
    const float* __restrict__ Wr, float* __restrict__ out) {
    __shared__ float a_sh[64][CC];
    __shared__ float x_sh[64][CC];
    int row0 = blockIdx.x * 64;
    int tid = threadIdx.x;
    for (int i = tid; i < 64 * CC / 4; i += 256) {
        int r = i >> 5, c4 = i & 31;
        int row = row0 + r;
        float4 av = make_float4(0.f, 0.f, 0.f, 0.f);
        float4 xv = make_float4(0.f, 0.f, 0.f, 0.f);
        if (row < NN) {
            av = ((const float4*)(aggr + (long long)row * CC))[c4];
            xv = ((const float4*)(xin + (long long)row * CC))[c4];
        }
        ((float4*)a_sh[r])[c4] = av;
        ((float4*)x_sh[r])[c4] = xv;
    }
    __syncthreads();

    int col = (tid & 31) * 4;
    int rg  = tid >> 5;
    float4 bv = *(const float4*)(bias + col);
    float acc[8][4];
#pragma unroll
    for (int r = 0; r < 8; ++r) {
        acc[r][0] = bv.x; acc[r][1] = bv.y; acc[r][2] = bv.z; acc[r][3] = bv.w;
    }
    for (int k = 0; k < CC; ++k) {
        float4 wl = *(const float4*)(Wl + k * CC + col);
        float4 wr = *(const float4*)(Wr + k * CC + col);
#pragma unroll
        for (int r = 0; r < 8; ++r) {
            float a  = a_sh[rg * 8 + r][k];
            float xx = x_sh[rg * 8 + r][k];
            acc[r][0] += a * wl.x + xx * wr.x;
            acc[r][1] += a * wl.y + xx * wr.y;
            acc[r][2] += a * wl.z + xx * wr.z;
            acc[r][3] += a * wl.w + xx * wr.w;
        }
    }
#pragma unroll
    for (int r = 0; r < 8; ++r) {
        int row = row0 + rg * 8 + r;
        if (row < NN) {
            float4 o;
            o.x = fmaxf(acc[r][0], 0.f);
            o.y = fmaxf(acc[r][1], 0.f);
            o.z = fmaxf(acc[r][2], 0.f);
            o.w = fmaxf(acc[r][3], 0.f);
            *(float4*)(out + (long long)row * CC + col) = o;
        }
    }
}

// ---------------- classifier: logits = h @ Wc + bc ----------------
__global__ __launch_bounds__(256) void k_cls(
    const float* __restrict__ h, const float* __restrict__ Wc,
    const float* __restrict__ bc, float* __restrict__ logits) {
    __shared__ float h_sh[16][CC];
    int row0 = blockIdx.x * 16;
    int tid = threadIdx.x;
    for (int i = tid; i < 16 * CC / 4; i += 256) {
        int r = i >> 5, c4 = i & 31;
        int row = row0 + r;
        float4 v = make_float4(0.f, 0.f, 0.f, 0.f);
        if (row < NN) v = ((const float4*)(h + (long long)row * CC))[c4];
        ((float4*)h_sh[r])[c4] = v;
    }
    __syncthreads();
    int col = (tid & 15) * 4;
    int r = tid >> 4;
    float4 bv = *(const float4*)(bc + col);
    float a0 = bv.x, a1 = bv.y, a2 = bv.z, a3 = bv.w;
    for (int k = 0; k < CC; ++k) {
        float hv = h_sh[r][k];
        float4 w = *(const float4*)(Wc + k * OC + col);
        a0 += hv * w.x; a1 += hv * w.y; a2 += hv * w.z; a3 += hv * w.w;
    }
    int row = row0 + r;
    if (row < NN) {
        *(float4*)(logits + (long long)row * OC + col) = make_float4(a0, a1, a2, a3);
    }
}

extern "C" void kernel_launch(void* const* d_in, const int* in_sizes, int n_in,
                              void* d_out, int out_size, void* d_ws, size_t ws_size,
                              hipStream_t stream) {
    const float* x_doc = (const float*)d_in[0];
    const int* ei = (const int*)d_in[2];
    const float* W1l = (const float*)d_in[4];
    const float* b1  = (const float*)d_in[5];
    const float* W1r = (const float*)d_in[6];
    const float* W2l = (const float*)d_in[7];
    const float* b2  = (const float*)d_in[8];
    const float* W2r = (const float*)d_in[9];
    const float* Wc  = (const float*)d_in[10];
    const float* bc  = (const float*)d_in[11];

    const int* src = ei;        // edge_index[0]
    const int* dst = ei + EE;   // edge_index[1]

    // workspace layout (floats first to keep 16B alignment for float4 loads)
    float* aggr = (float*)d_ws;                    // NN*CC
    float* h1   = aggr + (long long)NN * CC;       // NN*CC
    int* ideg   = (int*)(h1 + (long long)NN * CC); // NN
    int* off    = ideg + NN;                       // NN+1
    int* cursor = off + NN + 1;                    // NN
    int* partials = cursor + NN;                   // NB (pad to 256)
    int* ssrc   = partials + 256;                  // EE

    float* logits = (float*)d_out;                 // NN*OC
    float* h2     = logits + (long long)NN * OC;   // NN*CC (second tuple output)

    // ---- CSR build (per call; deterministic work) ----
    hipMemsetAsync(ideg, 0, NN * sizeof(int), stream);
    k_count<<<(EE + 255) / 256, 256, 0, stream>>>(dst, ideg);
    k_scan1<<<NB, 256, 0, stream>>>(ideg, partials);
    k_scan2<<<1, 64, 0, stream>>>(partials);
    k_scan3<<<NB, 256, 0, stream>>>(ideg, partials, off, cursor);
    k_place<<<(EE + 255) / 256, 256, 0, stream>>>(src, dst, cursor, ssrc);

    // ---- layer 1 ----
    k_gather<<<(NN + 3) / 4, 256, 0, stream>>>(off, ssrc, x_doc, aggr);
    k_layer<<<(NN + 63) / 64, 256, 0, stream>>>(aggr, x_doc, W1l, b1, W1r, h1);

    // ---- layer 2 ----
    k_gather<<<(NN + 3) / 4, 256, 0, stream>>>(off, ssrc, h1, aggr);
    k_layer<<<(NN + 63) / 64, 256, 0, stream>>>(aggr, h1, W2l, b2, W2r, h2);

    // ---- classifier ----
    k_cls<<<(NN + 15) / 16, 256, 0, stream>>>(h2, Wc, bc, logits);
}

// Round 3
// 224.302 us; speedup vs baseline: 13.4633x; 2.1327x over previous
//
#include <hip/hip_runtime.h>

#define NN 50000
#define CC 128
#define OC 64
#define EE 800000
#define NB 196  // ceil(NN/256)

typedef __attribute__((ext_vector_type(8))) short short8;
typedef __attribute__((ext_vector_type(4))) float f32x4;

__device__ __forceinline__ float bflo(uint v) { return __uint_as_float(v << 16); }
__device__ __forceinline__ float bfhi(uint v) { return __uint_as_float(v & 0xffff0000u); }
__device__ __forceinline__ ushort f2bf(float x) {
    uint u = __float_as_uint(x);
    return (ushort)((u + 0x7fffu + ((u >> 16) & 1u)) >> 16);
}

// ---------------- CSR build ----------------
__global__ void k_count(const int* __restrict__ dst, int* __restrict__ ideg) {
    int e = blockIdx.x * blockDim.x + threadIdx.x;
    if (e < EE) atomicAdd(&ideg[dst[e]], 1);
}

__global__ __launch_bounds__(256) void k_scan1(const int* __restrict__ ideg,
                                               int* __restrict__ partials) {
    __shared__ int sh[256];
    int idx = blockIdx.x * 256 + threadIdx.x;
    sh[threadIdx.x] = (idx < NN) ? ideg[idx] : 0;
    __syncthreads();
    for (int s = 128; s > 0; s >>= 1) {
        if (threadIdx.x < s) sh[threadIdx.x] += sh[threadIdx.x + s];
        __syncthreads();
    }
    if (threadIdx.x == 0) partials[blockIdx.x] = sh[0];
}

__global__ void k_scan2(int* __restrict__ partials) {
    if (threadIdx.x == 0 && blockIdx.x == 0) {
        int acc = 0;
        for (int i = 0; i < NB; ++i) { int v = partials[i]; partials[i] = acc; acc += v; }
    }
}

__global__ __launch_bounds__(256) void k_scan3(const int* __restrict__ ideg,
                                               const int* __restrict__ partials,
                                               int* __restrict__ off, int* __restrict__ cursor) {
    __shared__ int sh[256];
    int idx = blockIdx.x * 256 + threadIdx.x;
    int v = (idx < NN) ? ideg[idx] : 0;
    sh[threadIdx.x] = v;
    __syncthreads();
    for (int d = 1; d < 256; d <<= 1) {
        int t = (threadIdx.x >= d) ? sh[threadIdx.x - d] : 0;
        __syncthreads();
        sh[threadIdx.x] += t;
        __syncthreads();
    }
    int excl = sh[threadIdx.x] - v + partials[blockIdx.x];
    if (idx < NN) { off[idx] = excl; cursor[idx] = excl; }
    if (idx == NN - 1) off[NN] = excl + v;
}

__global__ void k_place(const int* __restrict__ src, const int* __restrict__ dst,
                        int* __restrict__ cursor, int* __restrict__ ssrc) {
    int e = blockIdx.x * blockDim.x + threadIdx.x;
    if (e < EE) {
        int p = atomicAdd(&cursor[dst[e]], 1);
        ssrc[p] = src[e];
    }
}

// ---------------- f32 -> bf16 convert ----------------
__global__ void k_cvt(const float* __restrict__ x, ushort* __restrict__ o) {
    int i = blockIdx.x * 256 + threadIdx.x;  // per 4 elems
    if (i >= NN * CC / 4) return;
    float4 v = ((const float4*)x)[i];
    ushort4 u;
    u.x = f2bf(v.x); u.y = f2bf(v.y); u.z = f2bf(v.z); u.w = f2bf(v.w);
    ((ushort4*)o)[i] = u;
}

// ---------------- weight pack into MFMA B-frag layout ----------------
// layer B = [Wl ; Wr] (256 x 128). frag (ks,n): lane l, elem j holds B[32ks+8kg+j][16n+l15]
__global__ void k_packw(const float* __restrict__ Wl, const float* __restrict__ Wr,
                        ushort* __restrict__ wp) {
    int t = blockIdx.x * 256 + threadIdx.x;
    if (t >= 4096) return;  // 8ks * 8n * 64l
    int l = t & 63, n = (t >> 6) & 7, ks = t >> 9;
    int kg = l >> 4, col = 16 * n + (l & 15);
    uint out[4];
#pragma unroll
    for (int jj = 0; jj < 4; ++jj) {
        int k = 32 * ks + 8 * kg + 2 * jj;
        float v0 = (k < 128) ? Wl[k * 128 + col] : Wr[(k - 128) * 128 + col];
        float v1 = (k + 1 < 128) ? Wl[(k + 1) * 128 + col] : Wr[(k + 1 - 128) * 128 + col];
        out[jj] = (uint)f2bf(v0) | ((uint)f2bf(v1) << 16);
    }
    *(uint4*)(wp + (long long)t * 8) = make_uint4(out[0], out[1], out[2], out[3]);
}

// cls B = Wc (128 x 64): frag (ks,n), ks<4, n<4
__global__ void k_packwc(const float* __restrict__ Wc, ushort* __restrict__ wp) {
    int t = blockIdx.x * 256 + threadIdx.x;
    if (t >= 1024) return;  // 4ks * 4n * 64l
    int l = t & 63, n = (t >> 6) & 3, ks = t >> 8;
    int kg = l >> 4, col = 16 * n + (l & 15);
    uint out[4];
#pragma unroll
    for (int jj = 0; jj < 4; ++jj) {
        int k = 32 * ks + 8 * kg + 2 * jj;
        out[jj] = (uint)f2bf(Wc[k * 64 + col]) | ((uint)f2bf(Wc[(k + 1) * 64 + col]) << 16);
    }
    *(uint4*)(wp + (long long)t * 8) = make_uint4(out[0], out[1], out[2], out[3]);
}

// ---------------- gather (bf16): aggr[i] = mean of neighbor rows ----------------
__global__ __launch_bounds__(256) void k_gather_bf(const int* __restrict__ off,
                                                   const int* __restrict__ ssrc,
                                                   const ushort* __restrict__ xb,
                                                   ushort* __restrict__ ab) {
    int wid = blockIdx.x * 4 + (threadIdx.x >> 6);
    int lane = threadIdx.x & 63;
    if (wid >= NN) return;
    int s0 = off[wid], s1 = off[wid + 1];
    float ax = 0.f, ay = 0.f;
    int j = s0;
    for (; j + 3 < s1; j += 4) {
        int sa = ssrc[j], sb = ssrc[j + 1], sc = ssrc[j + 2], sd = ssrc[j + 3];
        uint va = ((const uint*)xb)[(long long)sa * 64 + lane];
        uint vb = ((const uint*)xb)[(long long)sb * 64 + lane];
        uint vc = ((const uint*)xb)[(long long)sc * 64 + lane];
        uint vd = ((const uint*)xb)[(long long)sd * 64 + lane];
        ax += bflo(va) + bflo(vb) + bflo(vc) + bflo(vd);
        ay += bfhi(va) + bfhi(vb) + bfhi(vc) + bfhi(vd);
    }
    for (; j < s1; ++j) {
        uint va = ((const uint*)xb)[(long long)ssrc[j] * 64 + lane];
        ax += bflo(va); ay += bfhi(va);
    }
    float dinv = 1.0f / fmaxf((float)(s1 - s0), 1.0f);
    ((uint*)ab)[(long long)wid * 64 + lane] = (uint)f2bf(ax * dinv) | ((uint)f2bf(ay * dinv) << 16);
}

// ---------------- MFMA layer: out = relu([aggr|x] @ [Wl;Wr] + b) ----------------
// 64 rows/block, 4 waves (16 rows each), K=256, N=128.
// A staged in LDS bf16 [64][256] with byte ^= (row&7)<<4 swizzle.
__global__ __launch_bounds__(256) void k_layer_mfma(
    const ushort* __restrict__ abf, const ushort* __restrict__ xbf,
    const ushort* __restrict__ wp, const float* __restrict__ bias,
    ushort* __restrict__ hbf) {
    __shared__ uint4 a_sh4[2048];  // 32KB
    char* a_sh = (char*)a_sh4;
    int row0 = blockIdx.x * 64;
    int tid = threadIdx.x;
#pragma unroll
    for (int it = 0; it < 8; ++it) {
        int idx = tid + it * 256;        // 0..2047
        int r = idx >> 5, c = idx & 31;  // 32 x 16B chunks per row
        int row = row0 + r;
        uint4 v = make_uint4(0, 0, 0, 0);
        if (row < NN) {
            const ushort* srcp = (c < 16) ? (abf + (long long)row * 128 + c * 8)
                                          : (xbf + (long long)row * 128 + (c - 16) * 8);
            v = *(const uint4*)srcp;
        }
        *(uint4*)(a_sh + r * 512 + ((c * 16) ^ ((r & 7) << 4))) = v;
    }
    __syncthreads();

    int w = tid >> 6, l = tid & 63;
    int l15 = l & 15, kg = l >> 4;
    int lrow = 16 * w + l15;
    f32x4 acc[8];
#pragma unroll
    for (int n = 0; n < 8; ++n) {
        float b = bias[16 * n + l15];
        acc[n] = (f32x4){b, b, b, b};
    }
#pragma unroll
    for (int ks = 0; ks < 8; ++ks) {
        short8 af = *(const short8*)(a_sh + lrow * 512 + ((ks * 64 + kg * 16) ^ ((lrow & 7) << 4)));
        const short8* bp = ((const short8*)wp) + (ks * 8) * 64 + l;
#pragma unroll
        for (int n = 0; n < 8; ++n)
            acc[n] = __builtin_amdgcn_mfma_f32_16x16x32_bf16(af, bp[n * 64], acc[n], 0, 0, 0);
    }
#pragma unroll
    for (int n = 0; n < 8; ++n) {
        int col = 16 * n + l15;
#pragma unroll
        for (int r = 0; r < 4; ++r) {
            int row = row0 + 16 * w + kg * 4 + r;
            if (row < NN) hbf[(long long)row * CC + col] = f2bf(fmaxf(acc[n][r], 0.f));
        }
    }
}

// ---------------- MFMA layer2 + fused classifier ----------------
__global__ __launch_bounds__(256) void k_layer2_cls(
    const ushort* __restrict__ abf, const ushort* __restrict__ xbf,
    const ushort* __restrict__ wp2, const float* __restrict__ b2,
    const ushort* __restrict__ wpc, const float* __restrict__ bc,
    float* __restrict__ h2f, float* __restrict__ logits) {
    __shared__ uint4 a_sh4[2048];  // 32KB
    char* a_sh = (char*)a_sh4;
    int row0 = blockIdx.x * 64;
    int tid = threadIdx.x;
#pragma unroll
    for (int it = 0; it < 8; ++it) {
        int idx = tid + it * 256;
        int r = idx >> 5, c = idx & 31;
        int row = row0 + r;
        uint4 v = make_uint4(0, 0, 0, 0);
        if (row < NN) {
            const ushort* srcp = (c < 16) ? (abf + (long long)row * 128 + c * 8)
                                          : (xbf + (long long)row * 128 + (c - 16) * 8);
            v = *(const uint4*)srcp;
        }
        *(uint4*)(a_sh + r * 512 + ((c * 16) ^ ((r & 7) << 4))) = v;
    }
    __syncthreads();

    int w = tid >> 6, l = tid & 63;
    int l15 = l & 15, kg = l >> 4;
    int lrow = 16 * w + l15;
    f32x4 acc[8];
#pragma unroll
    for (int n = 0; n < 8; ++n) {
        float b = b2[16 * n + l15];
        acc[n] = (f32x4){b, b, b, b};
    }
#pragma unroll
    for (int ks = 0; ks < 8; ++ks) {
        short8 af = *(const short8*)(a_sh + lrow * 512 + ((ks * 64 + kg * 16) ^ ((lrow & 7) << 4)));
        const short8* bp = ((const short8*)wp2) + (ks * 8) * 64 + l;
#pragma unroll
        for (int n = 0; n < 8; ++n)
            acc[n] = __builtin_amdgcn_mfma_f32_16x16x32_bf16(af, bp[n * 64], acc[n], 0, 0, 0);
    }
    __syncthreads();  // all A-frag reads done; reuse LDS for cls A (16KB, [64][128] bf16)

    // epilogue: relu -> h2 f32 (global) + bf16 into cls LDS
#pragma unroll
    for (int n = 0; n < 8; ++n) {
        int col = 16 * n + l15;
#pragma unroll
        for (int r = 0; r < 4; ++r) {
            int lr = 16 * w + kg * 4 + r;
            int row = row0 + lr;
            float v = fmaxf(acc[n][r], 0.f);
            if (row < NN) h2f[(long long)row * CC + col] = v;
            *(ushort*)(a_sh + lr * 256 + ((col * 2) ^ ((lr & 7) << 4))) = f2bf(v);
        }
    }
    __syncthreads();

    // classifier: logits = h2 @ Wc + bc  (K=128, N=64)
    f32x4 acc2[4];
#pragma unroll
    for (int n = 0; n < 4; ++n) {
        float b = bc[16 * n + l15];
        acc2[n] = (f32x4){b, b, b, b};
    }
#pragma unroll
    for (int ks = 0; ks < 4; ++ks) {
        short8 af = *(const short8*)(a_sh + lrow * 256 + ((ks * 64 + kg * 16) ^ ((lrow & 7) << 4)));
        const short8* bp = ((const short8*)wpc) + (ks * 4) * 64 + l;
#pragma unroll
        for (int n = 0; n < 4; ++n)
            acc2[n] = __builtin_amdgcn_mfma_f32_16x16x32_bf16(af, bp[n * 64], acc2[n], 0, 0, 0);
    }
#pragma unroll
    for (int n = 0; n < 4; ++n) {
        int col = 16 * n + l15;
#pragma unroll
        for (int r = 0; r < 4; ++r) {
            int row = row0 + 16 * w + kg * 4 + r;
            if (row < NN) logits[(long long)row * OC + col] = acc2[n][r];
        }
    }
}

extern "C" void kernel_launch(void* const* d_in, const int* in_sizes, int n_in,
                              void* d_out, int out_size, void* d_ws, size_t ws_size,
                              hipStream_t stream) {
    const float* x_doc = (const float*)d_in[0];
    const int* ei = (const int*)d_in[2];
    const float* W1l = (const float*)d_in[4];
    const float* b1  = (const float*)d_in[5];
    const float* W1r = (const float*)d_in[6];
    const float* W2l = (const float*)d_in[7];
    const float* b2  = (const float*)d_in[8];
    const float* W2r = (const float*)d_in[9];
    const float* Wc  = (const float*)d_in[10];
    const float* bc  = (const float*)d_in[11];

    const int* src = ei;
    const int* dst = ei + EE;

    // workspace layout
    ushort* x_bf  = (ushort*)d_ws;                   // NN*CC
    ushort* aggr  = x_bf + (long long)NN * CC;       // NN*CC (reused both layers)
    ushort* h1_bf = aggr + (long long)NN * CC;       // NN*CC
    ushort* wp1   = h1_bf + (long long)NN * CC;      // 32768
    ushort* wp2   = wp1 + 32768;                     // 32768
    ushort* wpc   = wp2 + 32768;                     // 8192
    int* ideg     = (int*)(wpc + 8192);              // NN
    int* off      = ideg + NN;                       // NN+1
    int* cursor   = off + NN + 1;                    // NN
    int* partials = cursor + NN;                     // 256
    int* ssrc     = partials + 256;                  // EE

    float* logits = (float*)d_out;                   // NN*OC
    float* h2f    = logits + (long long)NN * OC;     // NN*CC

    // CSR build
    hipMemsetAsync(ideg, 0, NN * sizeof(int), stream);
    k_count<<<(EE + 255) / 256, 256, 0, stream>>>(dst, ideg);
    k_scan1<<<NB, 256, 0, stream>>>(ideg, partials);
    k_scan2<<<1, 64, 0, stream>>>(partials);
    k_scan3<<<NB, 256, 0, stream>>>(ideg, partials, off, cursor);
    k_place<<<(EE + 255) / 256, 256, 0, stream>>>(src, dst, cursor, ssrc);

    // converts + weight packs
    k_cvt<<<(NN * CC / 4 + 255) / 256, 256, 0, stream>>>(x_doc, x_bf);
    k_packw<<<16, 256, 0, stream>>>(W1l, W1r, wp1);
    k_packw<<<16, 256, 0, stream>>>(W2l, W2r, wp2);
    k_packwc<<<4, 256, 0, stream>>>(Wc, wpc);

    // layer 1
    k_gather_bf<<<(NN + 3) / 4, 256, 0, stream>>>(off, ssrc, x_bf, aggr);
    k_layer_mfma<<<(NN + 63) / 64, 256, 0, stream>>>(aggr, x_bf, wp1, b1, h1_bf);

    // layer 2 + classifier
    k_gather_bf<<<(NN + 3) / 4, 256, 0, stream>>>(off, ssrc, h1_bf, aggr);
    k_layer2_cls<<<(NN + 63) / 64, 256, 0, stream>>>(aggr, h1_bf, wp2, b2, wpc, bc, h2f, logits);
}

// Round 4
// 167.728 us; speedup vs baseline: 18.0044x; 1.3373x over previous
//
#include <hip/hip_runtime.h>

#define NN 50000
#define CC 128
#define OC 64
#define EE 800000
#define NBKT 196      // buckets of 256 nodes: ceil(50000/256)
#define CHUNK 4096
#define NBIN_BLK 196  // ceil(EE/CHUNK)

typedef __attribute__((ext_vector_type(8))) short short8;
typedef __attribute__((ext_vector_type(4))) float f32x4;

__device__ __forceinline__ float bflo(uint v) { return __uint_as_float(v << 16); }
__device__ __forceinline__ float bfhi(uint v) { return __uint_as_float(v & 0xffff0000u); }
__device__ __forceinline__ ushort f2bf(float x) {
    uint u = __float_as_uint(x);
    return (ushort)((u + 0x7fffu + ((u >> 16) & 1u)) >> 16);
}

// ---------------- CSR build: LDS-binned counting sort ----------------
__global__ __launch_bounds__(256) void k_hist(const int* __restrict__ dst,
                                              int* __restrict__ tot) {
    __shared__ int h[256];
    int tid = threadIdx.x;
    h[tid] = 0;
    __syncthreads();
    int e0 = blockIdx.x * CHUNK;
    for (int i = tid; i < CHUNK; i += 256) {
        int e = e0 + i;
        if (e < EE) atomicAdd(&h[dst[e] >> 8], 1);
    }
    __syncthreads();
    if (tid < NBKT && h[tid]) atomicAdd(&tot[tid], h[tid]);
}

__global__ __launch_bounds__(256) void k_scan196(const int* __restrict__ tot,
                                                 int* __restrict__ base,
                                                 int* __restrict__ gcur) {
    __shared__ int s[256];
    int tid = threadIdx.x;
    int v = (tid < NBKT) ? tot[tid] : 0;
    s[tid] = v;
    __syncthreads();
    for (int d = 1; d < 256; d <<= 1) {
        int t = (tid >= d) ? s[tid - d] : 0;
        __syncthreads();
        s[tid] += t;
        __syncthreads();
    }
    int excl = s[tid] - v;
    if (tid < NBKT) { base[tid] = excl; gcur[tid] = excl; }
    if (tid == NBKT - 1) base[NBKT] = s[tid];  // == EE
}

__global__ __launch_bounds__(256) void k_bin(const int* __restrict__ src,
                                             const int* __restrict__ dst,
                                             int* __restrict__ gcur,
                                             uint* __restrict__ binned) {
    __shared__ int h[256];
    __shared__ int gb[256];
    __shared__ int cur[256];
    int tid = threadIdx.x;
    h[tid] = 0;
    __syncthreads();
    int e0 = blockIdx.x * CHUNK;
    for (int i = tid; i < CHUNK; i += 256) {
        int e = e0 + i;
        if (e < EE) atomicAdd(&h[dst[e] >> 8], 1);
    }
    __syncthreads();
    if (tid < NBKT) {
        gb[tid] = h[tid] ? atomicAdd(&gcur[tid], h[tid]) : 0;
        cur[tid] = 0;
    }
    __syncthreads();
    for (int i = tid; i < CHUNK; i += 256) {
        int e = e0 + i;
        if (e < EE) {
            int d = dst[e];
            int b = d >> 8;
            int r = atomicAdd(&cur[b], 1);
            binned[gb[b] + r] = ((uint)(d & 255) << 16) | (uint)src[e];
        }
    }
}

__global__ __launch_bounds__(256) void k_fine(const int* __restrict__ base,
                                              const uint* __restrict__ binned,
                                              int* __restrict__ off,
                                              int* __restrict__ ssrc) {
    __shared__ int hist[256];
    __shared__ int sc[256];
    __shared__ int curs[256];
    int b = blockIdx.x, tid = threadIdx.x;
    int s = base[b], cnt = base[b + 1] - s;
    hist[tid] = 0;
    __syncthreads();
    for (int i = tid; i < cnt; i += 256) atomicAdd(&hist[binned[s + i] >> 16], 1);
    __syncthreads();
    int v = hist[tid];
    sc[tid] = v;
    __syncthreads();
    for (int d = 1; d < 256; d <<= 1) {
        int t = (tid >= d) ? sc[tid - d] : 0;
        __syncthreads();
        sc[tid] += t;
        __syncthreads();
    }
    int excl = sc[tid] - v;
    int idx = b * 256 + tid;
    if (idx <= NN) off[idx] = s + excl;
    curs[tid] = excl;
    __syncthreads();
    for (int i = tid; i < cnt; i += 256) {
        uint p = binned[s + i];
        int r = atomicAdd(&curs[p >> 16], 1);
        ssrc[s + r] = (int)(p & 0xffffu);
    }
}

// ---------------- f32 -> bf16 convert ----------------
__global__ void k_cvt(const float* __restrict__ x, ushort* __restrict__ o) {
    int i = blockIdx.x * 256 + threadIdx.x;
    if (i >= NN * CC / 4) return;
    float4 v = ((const float4*)x)[i];
    ushort4 u;
    u.x = f2bf(v.x); u.y = f2bf(v.y); u.z = f2bf(v.z); u.w = f2bf(v.w);
    ((ushort4*)o)[i] = u;
}

// ---------------- weight pack into MFMA B-frag layout ----------------
__global__ void k_packw(const float* __restrict__ Wl, const float* __restrict__ Wr,
                        ushort* __restrict__ wp) {
    int t = blockIdx.x * 256 + threadIdx.x;
    if (t >= 4096) return;
    int l = t & 63, n = (t >> 6) & 7, ks = t >> 9;
    int kg = l >> 4, col = 16 * n + (l & 15);
    uint out[4];
#pragma unroll
    for (int jj = 0; jj < 4; ++jj) {
        int k = 32 * ks + 8 * kg + 2 * jj;
        float v0 = (k < 128) ? Wl[k * 128 + col] : Wr[(k - 128) * 128 + col];
        float v1 = (k + 1 < 128) ? Wl[(k + 1) * 128 + col] : Wr[(k + 1 - 128) * 128 + col];
        out[jj] = (uint)f2bf(v0) | ((uint)f2bf(v1) << 16);
    }
    *(uint4*)(wp + (long long)t * 8) = make_uint4(out[0], out[1], out[2], out[3]);
}

__global__ void k_packwc(const float* __restrict__ Wc, ushort* __restrict__ wp) {
    int t = blockIdx.x * 256 + threadIdx.x;
    if (t >= 1024) return;
    int l = t & 63, n = (t >> 6) & 3, ks = t >> 8;
    int kg = l >> 4, col = 16 * n + (l & 15);
    uint out[4];
#pragma unroll
    for (int jj = 0; jj < 4; ++jj) {
        int k = 32 * ks + 8 * kg + 2 * jj;
        out[jj] = (uint)f2bf(Wc[k * 64 + col]) | ((uint)f2bf(Wc[(k + 1) * 64 + col]) << 16);
    }
    *(uint4*)(wp + (long long)t * 8) = make_uint4(out[0], out[1], out[2], out[3]);
}

// ---------------- gather (bf16): half-wave per edge-row ----------------
__global__ __launch_bounds__(256) void k_gather_bf(const int* __restrict__ off,
                                                   const int* __restrict__ ssrc,
                                                   const ushort* __restrict__ xb,
                                                   ushort* __restrict__ ab) {
    int wid = blockIdx.x * 4 + (threadIdx.x >> 6);
    if (wid >= NN) return;
    int lane = threadIdx.x & 63;
    int half = lane >> 5, l31 = lane & 31;
    int s0 = off[wid], s1 = off[wid + 1];
    float a0 = 0.f, a1 = 0.f, a2 = 0.f, a3 = 0.f;
    int j = s0 + half;
    for (; j + 2 < s1; j += 4) {        // 2 edges per half per iter
        int sa = ssrc[j], sb = ssrc[j + 2];
        uint2 va = ((const uint2*)(xb + (long long)sa * CC))[l31];
        uint2 vb = ((const uint2*)(xb + (long long)sb * CC))[l31];
        a0 += bflo(va.x) + bflo(vb.x); a1 += bfhi(va.x) + bfhi(vb.x);
        a2 += bflo(va.y) + bflo(vb.y); a3 += bfhi(va.y) + bfhi(vb.y);
    }
    if (j < s1) {
        int sa = ssrc[j];
        uint2 va = ((const uint2*)(xb + (long long)sa * CC))[l31];
        a0 += bflo(va.x); a1 += bfhi(va.x);
        a2 += bflo(va.y); a3 += bfhi(va.y);
    }
    a0 += __shfl_xor(a0, 32); a1 += __shfl_xor(a1, 32);
    a2 += __shfl_xor(a2, 32); a3 += __shfl_xor(a3, 32);
    if (half == 0) {
        float dinv = 1.0f / fmaxf((float)(s1 - s0), 1.0f);
        uint2 o;
        o.x = (uint)f2bf(a0 * dinv) | ((uint)f2bf(a1 * dinv) << 16);
        o.y = (uint)f2bf(a2 * dinv) | ((uint)f2bf(a3 * dinv) << 16);
        ((uint2*)(ab + (long long)wid * CC))[l31] = o;
    }
}

// ---------------- MFMA layer: out = relu([aggr|x] @ [Wl;Wr] + b) ----------------
__global__ __launch_bounds__(256) void k_layer_mfma(
    const ushort* __restrict__ abf, const ushort* __restrict__ xbf,
    const ushort* __restrict__ wp, const float* __restrict__ bias,
    ushort* __restrict__ hbf) {
    __shared__ uint4 a_sh4[2048];  // 32KB
    char* a_sh = (char*)a_sh4;
    int row0 = blockIdx.x * 64;
    int tid = threadIdx.x;
#pragma unroll
    for (int it = 0; it < 8; ++it) {
        int idx = tid + it * 256;
        int r = idx >> 5, c = idx & 31;
        int row = row0 + r;
        uint4 v = make_uint4(0, 0, 0, 0);
        if (row < NN) {
            const ushort* srcp = (c < 16) ? (abf + (long long)row * 128 + c * 8)
                                          : (xbf + (long long)row * 128 + (c - 16) * 8);
            v = *(const uint4*)srcp;
        }
        *(uint4*)(a_sh + r * 512 + ((c * 16) ^ ((r & 7) << 4))) = v;
    }
    __syncthreads();

    int w = tid >> 6, l = tid & 63;
    int l15 = l & 15, kg = l >> 4;
    int lrow = 16 * w + l15;
    f32x4 acc[8];
#pragma unroll
    for (int n = 0; n < 8; ++n) {
        float b = bias[16 * n + l15];
        acc[n] = (f32x4){b, b, b, b};
    }
#pragma unroll
    for (int ks = 0; ks < 8; ++ks) {
        short8 af = *(const short8*)(a_sh + lrow * 512 + ((ks * 64 + kg * 16) ^ ((lrow & 7) << 4)));
        const short8* bp = ((const short8*)wp) + (ks * 8) * 64 + l;
#pragma unroll
        for (int n = 0; n < 8; ++n)
            acc[n] = __builtin_amdgcn_mfma_f32_16x16x32_bf16(af, bp[n * 64], acc[n], 0, 0, 0);
    }
#pragma unroll
    for (int n = 0; n < 8; ++n) {
        int col = 16 * n + l15;
#pragma unroll
        for (int r = 0; r < 4; ++r) {
            int row = row0 + 16 * w + kg * 4 + r;
            if (row < NN) hbf[(long long)row * CC + col] = f2bf(fmaxf(acc[n][r], 0.f));
        }
    }
}

// ---------------- MFMA layer2 + fused classifier ----------------
__global__ __launch_bounds__(256) void k_layer2_cls(
    const ushort* __restrict__ abf, const ushort* __restrict__ xbf,
    const ushort* __restrict__ wp2, const float* __restrict__ b2,
    const ushort* __restrict__ wpc, const float* __restrict__ bc,
    float* __restrict__ h2f, float* __restrict__ logits) {
    __shared__ uint4 a_sh4[2048];  // 32KB
    char* a_sh = (char*)a_sh4;
    int row0 = blockIdx.x * 64;
    int tid = threadIdx.x;
#pragma unroll
    for (int it = 0; it < 8; ++it) {
        int idx = tid + it * 256;
        int r = idx >> 5, c = idx & 31;
        int row = row0 + r;
        uint4 v = make_uint4(0, 0, 0, 0);
        if (row < NN) {
            const ushort* srcp = (c < 16) ? (abf + (long long)row * 128 + c * 8)
                                          : (xbf + (long long)row * 128 + (c - 16) * 8);
            v = *(const uint4*)srcp;
        }
        *(uint4*)(a_sh + r * 512 + ((c * 16) ^ ((r & 7) << 4))) = v;
    }
    __syncthreads();

    int w = tid >> 6, l = tid & 63;
    int l15 = l & 15, kg = l >> 4;
    int lrow = 16 * w + l15;
    f32x4 acc[8];
#pragma unroll
    for (int n = 0; n < 8; ++n) {
        float b = b2[16 * n + l15];
        acc[n] = (f32x4){b, b, b, b};
    }
#pragma unroll
    for (int ks = 0; ks < 8; ++ks) {
        short8 af = *(const short8*)(a_sh + lrow * 512 + ((ks * 64 + kg * 16) ^ ((lrow & 7) << 4)));
        const short8* bp = ((const short8*)wp2) + (ks * 8) * 64 + l;
#pragma unroll
        for (int n = 0; n < 8; ++n)
            acc[n] = __builtin_amdgcn_mfma_f32_16x16x32_bf16(af, bp[n * 64], acc[n], 0, 0, 0);
    }
    __syncthreads();

#pragma unroll
    for (int n = 0; n < 8; ++n) {
        int col = 16 * n + l15;
#pragma unroll
        for (int r = 0; r < 4; ++r) {
            int lr = 16 * w + kg * 4 + r;
            int row = row0 + lr;
            float v = fmaxf(acc[n][r], 0.f);
            if (row < NN) h2f[(long long)row * CC + col] = v;
            *(ushort*)(a_sh + lr * 256 + ((col * 2) ^ ((lr & 7) << 4))) = f2bf(v);
        }
    }
    __syncthreads();

    f32x4 acc2[4];
#pragma unroll
    for (int n = 0; n < 4; ++n) {
        float b = bc[16 * n + l15];
        acc2[n] = (f32x4){b, b, b, b};
    }
#pragma unroll
    for (int ks = 0; ks < 4; ++ks) {
        short8 af = *(const short8*)(a_sh + lrow * 256 + ((ks * 64 + kg * 16) ^ ((lrow & 7) << 4)));
        const short8* bp = ((const short8*)wpc) + (ks * 4) * 64 + l;
#pragma unroll
        for (int n = 0; n < 4; ++n)
            acc2[n] = __builtin_amdgcn_mfma_f32_16x16x32_bf16(af, bp[n * 64], acc2[n], 0, 0, 0);
    }
#pragma unroll
    for (int n = 0; n < 4; ++n) {
        int col = 16 * n + l15;
#pragma unroll
        for (int r = 0; r < 4; ++r) {
            int row = row0 + 16 * w + kg * 4 + r;
            if (row < NN) logits[(long long)row * OC + col] = acc2[n][r];
        }
    }
}

extern "C" void kernel_launch(void* const* d_in, const int* in_sizes, int n_in,
                              void* d_out, int out_size, void* d_ws, size_t ws_size,
                              hipStream_t stream) {
    const float* x_doc = (const float*)d_in[0];
    const int* ei = (const int*)d_in[2];
    const float* W1l = (const float*)d_in[4];
    const float* b1  = (const float*)d_in[5];
    const float* W1r = (const float*)d_in[6];
    const float* W2l = (const float*)d_in[7];
    const float* b2  = (const float*)d_in[8];
    const float* W2r = (const float*)d_in[9];
    const float* Wc  = (const float*)d_in[10];
    const float* bc  = (const float*)d_in[11];

    const int* src = ei;
    const int* dst = ei + EE;

    // workspace layout
    ushort* x_bf  = (ushort*)d_ws;                   // NN*CC
    ushort* aggr  = x_bf + (long long)NN * CC;       // NN*CC
    ushort* h1_bf = aggr + (long long)NN * CC;       // NN*CC
    ushort* wp1   = h1_bf + (long long)NN * CC;      // 32768
    ushort* wp2   = wp1 + 32768;                     // 32768
    ushort* wpc   = wp2 + 32768;                     // 8192
    int* tot      = (int*)(wpc + 8192);              // 256
    int* base     = tot + 256;                       // NBKT+1 (pad 256)
    int* gcur     = base + 256;                      // 256
    int* off      = gcur + 256;                      // NN+1
    int* ssrc     = off + (NN + 1);                  // EE
    uint* binned  = (uint*)(ssrc + EE);              // EE

    float* logits = (float*)d_out;                   // NN*OC
    float* h2f    = logits + (long long)NN * OC;     // NN*CC

    // CSR build (binned counting sort)
    hipMemsetAsync(tot, 0, 256 * sizeof(int), stream);
    k_hist<<<NBIN_BLK, 256, 0, stream>>>(dst, tot);
    k_scan196<<<1, 256, 0, stream>>>(tot, base, gcur);
    k_bin<<<NBIN_BLK, 256, 0, stream>>>(src, dst, gcur, binned);
    k_fine<<<NBKT, 256, 0, stream>>>(base, binned, off, ssrc);

    // converts + weight packs
    k_cvt<<<(NN * CC / 4 + 255) / 256, 256, 0, stream>>>(x_doc, x_bf);
    k_packw<<<16, 256, 0, stream>>>(W1l, W1r, wp1);
    k_packw<<<16, 256, 0, stream>>>(W2l, W2r, wp2);
    k_packwc<<<4, 256, 0, stream>>>(Wc, wpc);

    // layer 1
    k_gather_bf<<<(NN + 3) / 4, 256, 0, stream>>>(off, ssrc, x_bf, aggr);
    k_layer_mfma<<<(NN + 63) / 64, 256, 0, stream>>>(aggr, x_bf, wp1, b1, h1_bf);

    // layer 2 + classifier
    k_gather_bf<<<(NN + 3) / 4, 256, 0, stream>>>(off, ssrc, h1_bf, aggr);
    k_layer2_cls<<<(NN + 63) / 64, 256, 0, stream>>>(aggr, h1_bf, wp2, b2, wpc, bc, h2f, logits);
}

// Round 5
// 151.183 us; speedup vs baseline: 19.9747x; 1.1094x over previous
//
#include <hip/hip_runtime.h>

#define NN 50000
#define CC 128
#define OC 64
#define EE 800000
#define NBKT 196      // buckets of 256 nodes: ceil(50000/256)
#define CHUNK 4096
#define NBIN_BLK 196  // ceil(EE/CHUNK)

typedef __attribute__((ext_vector_type(8))) short short8;
typedef __attribute__((ext_vector_type(4))) float f32x4;

__device__ __forceinline__ float bflo(uint v) { return __uint_as_float(v << 16); }
__device__ __forceinline__ float bfhi(uint v) { return __uint_as_float(v & 0xffff0000u); }
__device__ __forceinline__ ushort f2bf(float x) {
    uint u = __float_as_uint(x);
    return (ushort)((u + 0x7fffu + ((u >> 16) & 1u)) >> 16);
}

// ---------------- CSR build: LDS-binned counting sort ----------------
__global__ __launch_bounds__(256) void k_hist(const int* __restrict__ dst,
                                              int* __restrict__ tot) {
    __shared__ int h[256];
    int tid = threadIdx.x;
    h[tid] = 0;
    __syncthreads();
    int e0 = blockIdx.x * CHUNK;
    for (int i = tid; i < CHUNK; i += 256) {
        int e = e0 + i;
        if (e < EE) atomicAdd(&h[dst[e] >> 8], 1);
    }
    __syncthreads();
    if (tid < NBKT && h[tid]) atomicAdd(&tot[tid], h[tid]);
}

__global__ __launch_bounds__(256) void k_scan196(const int* __restrict__ tot,
                                                 int* __restrict__ base,
                                                 int* __restrict__ gcur) {
    __shared__ int s[256];
    int tid = threadIdx.x;
    int v = (tid < NBKT) ? tot[tid] : 0;
    s[tid] = v;
    __syncthreads();
    for (int d = 1; d < 256; d <<= 1) {
        int t = (tid >= d) ? s[tid - d] : 0;
        __syncthreads();
        s[tid] += t;
        __syncthreads();
    }
    int excl = s[tid] - v;
    if (tid < NBKT) { base[tid] = excl; gcur[tid] = excl; }
    if (tid == NBKT - 1) base[NBKT] = s[tid];  // == EE
}

__global__ __launch_bounds__(256) void k_bin(const int* __restrict__ src,
                                             const int* __restrict__ dst,
                                             int* __restrict__ gcur,
                                             uint* __restrict__ binned) {
    __shared__ int h[256];
    __shared__ int gb[256];
    __shared__ int cur[256];
    int tid = threadIdx.x;
    h[tid] = 0;
    __syncthreads();
    int e0 = blockIdx.x * CHUNK;
    for (int i = tid; i < CHUNK; i += 256) {
        int e = e0 + i;
        if (e < EE) atomicAdd(&h[dst[e] >> 8], 1);
    }
    __syncthreads();
    if (tid < NBKT) {
        gb[tid] = h[tid] ? atomicAdd(&gcur[tid], h[tid]) : 0;
        cur[tid] = 0;
    }
    __syncthreads();
    for (int i = tid; i < CHUNK; i += 256) {
        int e = e0 + i;
        if (e < EE) {
            int d = dst[e];
            int b = d >> 8;
            int r = atomicAdd(&cur[b], 1);
            binned[gb[b] + r] = ((uint)(d & 255) << 16) | (uint)src[e];
        }
    }
}

__global__ __launch_bounds__(256) void k_fine(const int* __restrict__ base,
                                              const uint* __restrict__ binned,
                                              int* __restrict__ off,
                                              int* __restrict__ ssrc) {
    __shared__ int hist[256];
    __shared__ int sc[256];
    __shared__ int curs[256];
    int b = blockIdx.x, tid = threadIdx.x;
    int s = base[b], cnt = base[b + 1] - s;
    hist[tid] = 0;
    __syncthreads();
    for (int i = tid; i < cnt; i += 256) atomicAdd(&hist[binned[s + i] >> 16], 1);
    __syncthreads();
    int v = hist[tid];
    sc[tid] = v;
    __syncthreads();
    for (int d = 1; d < 256; d <<= 1) {
        int t = (tid >= d) ? sc[tid - d] : 0;
        __syncthreads();
        sc[tid] += t;
        __syncthreads();
    }
    int excl = sc[tid] - v;
    int idx = b * 256 + tid;
    if (idx <= NN) off[idx] = s + excl;
    curs[tid] = excl;
    __syncthreads();
    for (int i = tid; i < cnt; i += 256) {
        uint p = binned[s + i];
        int r = atomicAdd(&curs[p >> 16], 1);
        ssrc[s + r] = (int)(p & 0xffffu);
    }
}

// ---------------- fused prep: x->bf16 convert + all weight packs ----------------
// blocks [0,6250): cvt; [6250,6266): pack W1; [6266,6282): pack W2; [6282,6286): pack Wc
__device__ __forceinline__ void packw_body(const float* __restrict__ Wl,
                                           const float* __restrict__ Wr,
                                           ushort* __restrict__ wp, int t) {
    int l = t & 63, n = (t >> 6) & 7, ks = t >> 9;
    int kg = l >> 4, col = 16 * n + (l & 15);
    uint out[4];
#pragma unroll
    for (int jj = 0; jj < 4; ++jj) {
        int k = 32 * ks + 8 * kg + 2 * jj;
        float v0 = (k < 128) ? Wl[k * 128 + col] : Wr[(k - 128) * 128 + col];
        float v1 = (k + 1 < 128) ? Wl[(k + 1) * 128 + col] : Wr[(k + 1 - 128) * 128 + col];
        out[jj] = (uint)f2bf(v0) | ((uint)f2bf(v1) << 16);
    }
    *(uint4*)(wp + (long long)t * 8) = make_uint4(out[0], out[1], out[2], out[3]);
}

__global__ __launch_bounds__(256) void k_prep(
    const float* __restrict__ x, ushort* __restrict__ xb,
    const float* __restrict__ W1l, const float* __restrict__ W1r, ushort* __restrict__ wp1,
    const float* __restrict__ W2l, const float* __restrict__ W2r, ushort* __restrict__ wp2,
    const float* __restrict__ Wc, ushort* __restrict__ wpc) {
    int b = blockIdx.x, tid = threadIdx.x;
    if (b < 6250) {
        int i = b * 256 + tid;  // NN*CC/4 = 1,600,000 exactly
        float4 v = ((const float4*)x)[i];
        ushort4 u;
        u.x = f2bf(v.x); u.y = f2bf(v.y); u.z = f2bf(v.z); u.w = f2bf(v.w);
        ((ushort4*)xb)[i] = u;
    } else if (b < 6266) {
        packw_body(W1l, W1r, wp1, (b - 6250) * 256 + tid);
    } else if (b < 6282) {
        packw_body(W2l, W2r, wp2, (b - 6266) * 256 + tid);
    } else {
        int t = (b - 6282) * 256 + tid;  // < 1024
        int l = t & 63, n = (t >> 6) & 3, ks = t >> 8;
        int kg = l >> 4, col = 16 * n + (l & 15);
        uint out[4];
#pragma unroll
        for (int jj = 0; jj < 4; ++jj) {
            int k = 32 * ks + 8 * kg + 2 * jj;
            out[jj] = (uint)f2bf(Wc[k * 64 + col]) | ((uint)f2bf(Wc[(k + 1) * 64 + col]) << 16);
        }
        *(uint4*)(wpc + (long long)t * 8) = make_uint4(out[0], out[1], out[2], out[3]);
    }
}

// ---------------- gather (bf16): 16-lane group per edge-row, 2-deep ILP ----------------
__global__ __launch_bounds__(256) void k_gather_bf(const int* __restrict__ off,
                                                   const int* __restrict__ ssrc,
                                                   const ushort* __restrict__ xb,
                                                   ushort* __restrict__ ab) {
    int wid = blockIdx.x * 4 + (threadIdx.x >> 6);
    if (wid >= NN) return;
    int lane = threadIdx.x & 63;
    int g = lane >> 4, l15 = lane & 15;
    int s0 = off[wid], s1 = off[wid + 1];
    float a0 = 0.f, a1 = 0.f, a2 = 0.f, a3 = 0.f;
    float a4 = 0.f, a5 = 0.f, a6 = 0.f, a7 = 0.f;
    int j = s0 + g;
    for (; j + 4 < s1; j += 8) {   // 2 rows in flight per group (8 per wave)
        int sa = ssrc[j], sb = ssrc[j + 4];
        uint4 va = ((const uint4*)(xb + (long long)sa * CC))[l15];
        uint4 vb = ((const uint4*)(xb + (long long)sb * CC))[l15];
        a0 += bflo(va.x) + bflo(vb.x); a1 += bfhi(va.x) + bfhi(vb.x);
        a2 += bflo(va.y) + bflo(vb.y); a3 += bfhi(va.y) + bfhi(vb.y);
        a4 += bflo(va.z) + bflo(vb.z); a5 += bfhi(va.z) + bfhi(vb.z);
        a6 += bflo(va.w) + bflo(vb.w); a7 += bfhi(va.w) + bfhi(vb.w);
    }
    if (j < s1) {
        int sa = ssrc[j];
        uint4 va = ((const uint4*)(xb + (long long)sa * CC))[l15];
        a0 += bflo(va.x); a1 += bfhi(va.x);
        a2 += bflo(va.y); a3 += bfhi(va.y);
        a4 += bflo(va.z); a5 += bfhi(va.z);
        a6 += bflo(va.w); a7 += bfhi(va.w);
    }
    // reduce across the 4 groups
    a0 += __shfl_xor(a0, 16); a1 += __shfl_xor(a1, 16);
    a2 += __shfl_xor(a2, 16); a3 += __shfl_xor(a3, 16);
    a4 += __shfl_xor(a4, 16); a5 += __shfl_xor(a5, 16);
    a6 += __shfl_xor(a6, 16); a7 += __shfl_xor(a7, 16);
    a0 += __shfl_xor(a0, 32); a1 += __shfl_xor(a1, 32);
    a2 += __shfl_xor(a2, 32); a3 += __shfl_xor(a3, 32);
    a4 += __shfl_xor(a4, 32); a5 += __shfl_xor(a5, 32);
    a6 += __shfl_xor(a6, 32); a7 += __shfl_xor(a7, 32);
    if (g == 0) {
        float dinv = 1.0f / fmaxf((float)(s1 - s0), 1.0f);
        uint4 o;
        o.x = (uint)f2bf(a0 * dinv) | ((uint)f2bf(a1 * dinv) << 16);
        o.y = (uint)f2bf(a2 * dinv) | ((uint)f2bf(a3 * dinv) << 16);
        o.z = (uint)f2bf(a4 * dinv) | ((uint)f2bf(a5 * dinv) << 16);
        o.w = (uint)f2bf(a6 * dinv) | ((uint)f2bf(a7 * dinv) << 16);
        ((uint4*)(ab + (long long)wid * CC))[l15] = o;
    }
}

// ---------------- MFMA layer: out = relu([aggr|x] @ [Wl;Wr] + b) ----------------
__global__ __launch_bounds__(256) void k_layer_mfma(
    const ushort* __restrict__ abf, const ushort* __restrict__ xbf,
    const ushort* __restrict__ wp, const float* __restrict__ bias,
    ushort* __restrict__ hbf) {
    __shared__ uint4 a_sh4[2048];  // 32KB
    char* a_sh = (char*)a_sh4;
    int row0 = blockIdx.x * 64;
    int tid = threadIdx.x;
#pragma unroll
    for (int it = 0; it < 8; ++it) {
        int idx = tid + it * 256;
        int r = idx >> 5, c = idx & 31;
        int row = row0 + r;
        uint4 v = make_uint4(0, 0, 0, 0);
        if (row < NN) {
            const ushort* srcp = (c < 16) ? (abf + (long long)row * 128 + c * 8)
                                          : (xbf + (long long)row * 128 + (c - 16) * 8);
            v = *(const uint4*)srcp;
        }
        *(uint4*)(a_sh + r * 512 + ((c * 16) ^ ((r & 7) << 4))) = v;
    }
    __syncthreads();

    int w = tid >> 6, l = tid & 63;
    int l15 = l & 15, kg = l >> 4;
    int lrow = 16 * w + l15;
    f32x4 acc[8];
#pragma unroll
    for (int n = 0; n < 8; ++n) {
        float b = bias[16 * n + l15];
        acc[n] = (f32x4){b, b, b, b};
    }
#pragma unroll
    for (int ks = 0; ks < 8; ++ks) {
        short8 af = *(const short8*)(a_sh + lrow * 512 + ((ks * 64 + kg * 16) ^ ((lrow & 7) << 4)));
        const short8* bp = ((const short8*)wp) + (ks * 8) * 64 + l;
#pragma unroll
        for (int n = 0; n < 8; ++n)
            acc[n] = __builtin_amdgcn_mfma_f32_16x16x32_bf16(af, bp[n * 64], acc[n], 0, 0, 0);
    }
#pragma unroll
    for (int n = 0; n < 8; ++n) {
        int col = 16 * n + l15;
#pragma unroll
        for (int r = 0; r < 4; ++r) {
            int row = row0 + 16 * w + kg * 4 + r;
            if (row < NN) hbf[(long long)row * CC + col] = f2bf(fmaxf(acc[n][r], 0.f));
        }
    }
}

// ---------------- MFMA layer2 + fused classifier ----------------
__global__ __launch_bounds__(256) void k_layer2_cls(
    const ushort* __restrict__ abf, const ushort* __restrict__ xbf,
    const ushort* __restrict__ wp2, const float* __restrict__ b2,
    const ushort* __restrict__ wpc, const float* __restrict__ bc,
    float* __restrict__ h2f, float* __restrict__ logits) {
    __shared__ uint4 a_sh4[2048];  // 32KB
    char* a_sh = (char*)a_sh4;
    int row0 = blockIdx.x * 64;
    int tid = threadIdx.x;
#pragma unroll
    for (int it = 0; it < 8; ++it) {
        int idx = tid + it * 256;
        int r = idx >> 5, c = idx & 31;
        int row = row0 + r;
        uint4 v = make_uint4(0, 0, 0, 0);
        if (row < NN) {
            const ushort* srcp = (c < 16) ? (abf + (long long)row * 128 + c * 8)
                                          : (xbf + (long long)row * 128 + (c - 16) * 8);
            v = *(const uint4*)srcp;
        }
        *(uint4*)(a_sh + r * 512 + ((c * 16) ^ ((r & 7) << 4))) = v;
    }
    __syncthreads();

    int w = tid >> 6, l = tid & 63;
    int l15 = l & 15, kg = l >> 4;
    int lrow = 16 * w + l15;
    f32x4 acc[8];
#pragma unroll
    for (int n = 0; n < 8; ++n) {
        float b = b2[16 * n + l15];
        acc[n] = (f32x4){b, b, b, b};
    }
#pragma unroll
    for (int ks = 0; ks < 8; ++ks) {
        short8 af = *(const short8*)(a_sh + lrow * 512 + ((ks * 64 + kg * 16) ^ ((lrow & 7) << 4)));
        const short8* bp = ((const short8*)wp2) + (ks * 8) * 64 + l;
#pragma unroll
        for (int n = 0; n < 8; ++n)
            acc[n] = __builtin_amdgcn_mfma_f32_16x16x32_bf16(af, bp[n * 64], acc[n], 0, 0, 0);
    }
    __syncthreads();

#pragma unroll
    for (int n = 0; n < 8; ++n) {
        int col = 16 * n + l15;
#pragma unroll
        for (int r = 0; r < 4; ++r) {
            int lr = 16 * w + kg * 4 + r;
            int row = row0 + lr;
            float v = fmaxf(acc[n][r], 0.f);
            if (row < NN) h2f[(long long)row * CC + col] = v;
            *(ushort*)(a_sh + lr * 256 + ((col * 2) ^ ((lr & 7) << 4))) = f2bf(v);
        }
    }
    __syncthreads();

    f32x4 acc2[4];
#pragma unroll
    for (int n = 0; n < 4; ++n) {
        float b = bc[16 * n + l15];
        acc2[n] = (f32x4){b, b, b, b};
    }
#pragma unroll
    for (int ks = 0; ks < 4; ++ks) {
        short8 af = *(const short8*)(a_sh + lrow * 256 + ((ks * 64 + kg * 16) ^ ((lrow & 7) << 4)));
        const short8* bp = ((const short8*)wpc) + (ks * 4) * 64 + l;
#pragma unroll
        for (int n = 0; n < 4; ++n)
            acc2[n] = __builtin_amdgcn_mfma_f32_16x16x32_bf16(af, bp[n * 64], acc2[n], 0, 0, 0);
    }
#pragma unroll
    for (int n = 0; n < 4; ++n) {
        int col = 16 * n + l15;
#pragma unroll
        for (int r = 0; r < 4; ++r) {
            int row = row0 + 16 * w + kg * 4 + r;
            if (row < NN) logits[(long long)row * OC + col] = acc2[n][r];
        }
    }
}

extern "C" void kernel_launch(void* const* d_in, const int* in_sizes, int n_in,
                              void* d_out, int out_size, void* d_ws, size_t ws_size,
                              hipStream_t stream) {
    const float* x_doc = (const float*)d_in[0];
    const int* ei = (const int*)d_in[2];
    const float* W1l = (const float*)d_in[4];
    const float* b1  = (const float*)d_in[5];
    const float* W1r = (const float*)d_in[6];
    const float* W2l = (const float*)d_in[7];
    const float* b2  = (const float*)d_in[8];
    const float* W2r = (const float*)d_in[9];
    const float* Wc  = (const float*)d_in[10];
    const float* bc  = (const float*)d_in[11];

    const int* src = ei;
    const int* dst = ei + EE;

    // workspace layout
    ushort* x_bf  = (ushort*)d_ws;                   // NN*CC
    ushort* aggr  = x_bf + (long long)NN * CC;       // NN*CC
    ushort* h1_bf = aggr + (long long)NN * CC;       // NN*CC
    ushort* wp1   = h1_bf + (long long)NN * CC;      // 32768
    ushort* wp2   = wp1 + 32768;                     // 32768
    ushort* wpc   = wp2 + 32768;                     // 8192
    int* tot      = (int*)(wpc + 8192);              // 256
    int* base     = tot + 256;                       // NBKT+1 (pad 256)
    int* gcur     = base + 256;                      // 256
    int* off      = gcur + 256;                      // NN+1
    int* ssrc     = off + (NN + 1);                  // EE
    uint* binned  = (uint*)(ssrc + EE);              // EE

    float* logits = (float*)d_out;                   // NN*OC
    float* h2f    = logits + (long long)NN * OC;     // NN*CC

    // CSR build (binned counting sort)
    hipMemsetAsync(tot, 0, 256 * sizeof(int), stream);
    k_hist<<<NBIN_BLK, 256, 0, stream>>>(dst, tot);
    k_scan196<<<1, 256, 0, stream>>>(tot, base, gcur);
    k_bin<<<NBIN_BLK, 256, 0, stream>>>(src, dst, gcur, binned);
    k_fine<<<NBKT, 256, 0, stream>>>(base, binned, off, ssrc);

    // fused convert + weight packs
    k_prep<<<6286, 256, 0, stream>>>(x_doc, x_bf, W1l, W1r, wp1, W2l, W2r, wp2, Wc, wpc);

    // layer 1
    k_gather_bf<<<(NN + 3) / 4, 256, 0, stream>>>(off, ssrc, x_bf, aggr);
    k_layer_mfma<<<(NN + 63) / 64, 256, 0, stream>>>(aggr, x_bf, wp1, b1, h1_bf);

    // layer 2 + classifier
    k_gather_bf<<<(NN + 3) / 4, 256, 0, stream>>>(off, ssrc, h1_bf, aggr);
    k_layer2_cls<<<(NN + 63) / 64, 256, 0, stream>>>(aggr, h1_bf, wp2, b2, wpc, bc, h2f, logits);
}

// Round 6
// 137.926 us; speedup vs baseline: 21.8946x; 1.0961x over previous
//
#include <hip/hip_runtime.h>

#define NN 50000
#define CC 128
#define OC 64
#define EE 800000
#define NBKT 196      // buckets of 256 nodes
#define CAP 8192      // padded per-bucket capacity (mean 4096, sigma 64)
#define CHUNK 4096
#define NBIN_BLK 196  // ceil(EE/CHUNK)

typedef __attribute__((ext_vector_type(8))) short short8;
typedef __attribute__((ext_vector_type(4))) float f32x4;

__device__ __forceinline__ float bflo(uint v) { return __uint_as_float(v << 16); }
__device__ __forceinline__ float bfhi(uint v) { return __uint_as_float(v & 0xffff0000u); }
__device__ __forceinline__ ushort f2bf(float x) {
    uint u = __float_as_uint(x);
    return (ushort)((u + 0x7fffu + ((u >> 16) & 1u)) >> 16);
}

// ---------------- binning: one pass, padded bucket segments ----------------
__global__ __launch_bounds__(256) void k_bin(const int* __restrict__ src,
                                             const int* __restrict__ dst,
                                             int* __restrict__ gcnt,
                                             uint* __restrict__ binned) {
    __shared__ int h[256];
    __shared__ int gb[256];
    __shared__ int cur[256];
    int tid = threadIdx.x;
    h[tid] = 0;
    __syncthreads();
    int e0 = blockIdx.x * CHUNK;
    for (int i = tid; i < CHUNK; i += 256) {
        int e = e0 + i;
        if (e < EE) atomicAdd(&h[dst[e] >> 8], 1);
    }
    __syncthreads();
    if (tid < NBKT) {
        gb[tid] = h[tid] ? (tid * CAP + atomicAdd(&gcnt[tid], h[tid])) : 0;
        cur[tid] = 0;
    }
    __syncthreads();
    for (int i = tid; i < CHUNK; i += 256) {
        int e = e0 + i;
        if (e < EE) {
            int d = dst[e];
            int b = d >> 8;
            int r = atomicAdd(&cur[b], 1);
            binned[gb[b] + r] = ((uint)(d & 255) << 16) | (uint)src[e];
        }
    }
}

// ---------------- fine sort within bucket -> per-node [start,end) ----------------
__global__ __launch_bounds__(256) void k_fine(const int* __restrict__ gcnt,
                                              const uint* __restrict__ binned,
                                              int* __restrict__ offs,
                                              int* __restrict__ offe,
                                              int* __restrict__ ssrc) {
    __shared__ int hist[256];
    __shared__ int sc[256];
    __shared__ int curs[256];
    int b = blockIdx.x, tid = threadIdx.x;
    int s = b * CAP, cnt = gcnt[b];
    hist[tid] = 0;
    __syncthreads();
    for (int i = tid; i < cnt; i += 256) atomicAdd(&hist[binned[s + i] >> 16], 1);
    __syncthreads();
    int v = hist[tid];
    sc[tid] = v;
    __syncthreads();
    for (int d = 1; d < 256; d <<= 1) {
        int t = (tid >= d) ? sc[tid - d] : 0;
        __syncthreads();
        sc[tid] += t;
        __syncthreads();
    }
    int excl = sc[tid] - v;
    int idx = b * 256 + tid;
    if (idx < NN) { offs[idx] = s + excl; offe[idx] = s + excl + v; }
    curs[tid] = excl;
    __syncthreads();
    for (int i = tid; i < cnt; i += 256) {
        uint p = binned[s + i];
        int r = atomicAdd(&curs[p >> 16], 1);
        ssrc[s + r] = (int)(p & 0xffffu);
    }
}

// ---------------- fused prep: x->bf16 convert + all weight packs ----------------
__device__ __forceinline__ void packw_body(const float* __restrict__ Wl,
                                           const float* __restrict__ Wr,
                                           ushort* __restrict__ wp, int t) {
    int l = t & 63, n = (t >> 6) & 7, ks = t >> 9;
    int kg = l >> 4, col = 16 * n + (l & 15);
    uint out[4];
#pragma unroll
    for (int jj = 0; jj < 4; ++jj) {
        int k = 32 * ks + 8 * kg + 2 * jj;
        float v0 = (k < 128) ? Wl[k * 128 + col] : Wr[(k - 128) * 128 + col];
        float v1 = (k + 1 < 128) ? Wl[(k + 1) * 128 + col] : Wr[(k + 1 - 128) * 128 + col];
        out[jj] = (uint)f2bf(v0) | ((uint)f2bf(v1) << 16);
    }
    *(uint4*)(wp + (long long)t * 8) = make_uint4(out[0], out[1], out[2], out[3]);
}

__global__ __launch_bounds__(256) void k_prep(
    const float* __restrict__ x, ushort* __restrict__ xb,
    const float* __restrict__ W1l, const float* __restrict__ W1r, ushort* __restrict__ wp1,
    const float* __restrict__ W2l, const float* __restrict__ W2r, ushort* __restrict__ wp2,
    const float* __restrict__ Wc, ushort* __restrict__ wpc) {
    int b = blockIdx.x, tid = threadIdx.x;
    if (b < 6250) {
        int i = b * 256 + tid;  // NN*CC/4 = 1,600,000 exactly
        float4 v = ((const float4*)x)[i];
        ushort4 u;
        u.x = f2bf(v.x); u.y = f2bf(v.y); u.z = f2bf(v.z); u.w = f2bf(v.w);
        ((ushort4*)xb)[i] = u;
    } else if (b < 6266) {
        packw_body(W1l, W1r, wp1, (b - 6250) * 256 + tid);
    } else if (b < 6282) {
        packw_body(W2l, W2r, wp2, (b - 6266) * 256 + tid);
    } else {
        int t = (b - 6282) * 256 + tid;  // < 1024
        int l = t & 63, n = (t >> 6) & 3, ks = t >> 8;
        int kg = l >> 4, col = 16 * n + (l & 15);
        uint out[4];
#pragma unroll
        for (int jj = 0; jj < 4; ++jj) {
            int k = 32 * ks + 8 * kg + 2 * jj;
            out[jj] = (uint)f2bf(Wc[k * 64 + col]) | ((uint)f2bf(Wc[(k + 1) * 64 + col]) << 16);
        }
        *(uint4*)(wpc + (long long)t * 8) = make_uint4(out[0], out[1], out[2], out[3]);
    }
}

// ---------------- gather (bf16): one 16-lane group per node, 4-deep ILP ----------------
__global__ __launch_bounds__(256) void k_gather_bf(const int* __restrict__ offs,
                                                   const int* __restrict__ offe,
                                                   const int* __restrict__ ssrc,
                                                   const ushort* __restrict__ xb,
                                                   ushort* __restrict__ ab) {
    int node = blockIdx.x * 16 + (threadIdx.x >> 4);
    if (node >= NN) return;
    int l15 = threadIdx.x & 15;
    int s0 = offs[node], s1 = offe[node];
    float a0 = 0.f, a1 = 0.f, a2 = 0.f, a3 = 0.f;
    float a4 = 0.f, a5 = 0.f, a6 = 0.f, a7 = 0.f;
    int j = s0;
    for (; j + 3 < s1; j += 4) {   // 4 rows in flight per group (16 per wave)
        int sa = ssrc[j], sb = ssrc[j + 1], sc = ssrc[j + 2], sd = ssrc[j + 3];
        uint4 va = ((const uint4*)(xb + (long long)sa * CC))[l15];
        uint4 vb = ((const uint4*)(xb + (long long)sb * CC))[l15];
        uint4 vc = ((const uint4*)(xb + (long long)sc * CC))[l15];
        uint4 vd = ((const uint4*)(xb + (long long)sd * CC))[l15];
        a0 += bflo(va.x) + bflo(vb.x) + bflo(vc.x) + bflo(vd.x);
        a1 += bfhi(va.x) + bfhi(vb.x) + bfhi(vc.x) + bfhi(vd.x);
        a2 += bflo(va.y) + bflo(vb.y) + bflo(vc.y) + bflo(vd.y);
        a3 += bfhi(va.y) + bfhi(vb.y) + bfhi(vc.y) + bfhi(vd.y);
        a4 += bflo(va.z) + bflo(vb.z) + bflo(vc.z) + bflo(vd.z);
        a5 += bfhi(va.z) + bfhi(vb.z) + bfhi(vc.z) + bfhi(vd.z);
        a6 += bflo(va.w) + bflo(vb.w) + bflo(vc.w) + bflo(vd.w);
        a7 += bfhi(va.w) + bfhi(vb.w) + bfhi(vc.w) + bfhi(vd.w);
    }
    if (j + 1 < s1) {
        int sa = ssrc[j], sb = ssrc[j + 1];
        uint4 va = ((const uint4*)(xb + (long long)sa * CC))[l15];
        uint4 vb = ((const uint4*)(xb + (long long)sb * CC))[l15];
        a0 += bflo(va.x) + bflo(vb.x); a1 += bfhi(va.x) + bfhi(vb.x);
        a2 += bflo(va.y) + bflo(vb.y); a3 += bfhi(va.y) + bfhi(vb.y);
        a4 += bflo(va.z) + bflo(vb.z); a5 += bfhi(va.z) + bfhi(vb.z);
        a6 += bflo(va.w) + bflo(vb.w); a7 += bfhi(va.w) + bfhi(vb.w);
        j += 2;
    }
    if (j < s1) {
        int sa = ssrc[j];
        uint4 va = ((const uint4*)(xb + (long long)sa * CC))[l15];
        a0 += bflo(va.x); a1 += bfhi(va.x);
        a2 += bflo(va.y); a3 += bfhi(va.y);
        a4 += bflo(va.z); a5 += bfhi(va.z);
        a6 += bflo(va.w); a7 += bfhi(va.w);
    }
    float dinv = 1.0f / fmaxf((float)(s1 - s0), 1.0f);
    uint4 o;
    o.x = (uint)f2bf(a0 * dinv) | ((uint)f2bf(a1 * dinv) << 16);
    o.y = (uint)f2bf(a2 * dinv) | ((uint)f2bf(a3 * dinv) << 16);
    o.z = (uint)f2bf(a4 * dinv) | ((uint)f2bf(a5 * dinv) << 16);
    o.w = (uint)f2bf(a6 * dinv) | ((uint)f2bf(a7 * dinv) << 16);
    ((uint4*)(ab + (long long)node * CC))[l15] = o;
}

// ---------------- MFMA layer: out = relu([aggr|x] @ [Wl;Wr] + b) ----------------
__global__ __launch_bounds__(256) void k_layer_mfma(
    const ushort* __restrict__ abf, const ushort* __restrict__ xbf,
    const ushort* __restrict__ wp, const float* __restrict__ bias,
    ushort* __restrict__ hbf) {
    __shared__ uint4 a_sh4[2048];  // 32KB
    char* a_sh = (char*)a_sh4;
    int row0 = blockIdx.x * 64;
    int tid = threadIdx.x;
#pragma unroll
    for (int it = 0; it < 8; ++it) {
        int idx = tid + it * 256;
        int r = idx >> 5, c = idx & 31;
        int row = row0 + r;
        uint4 v = make_uint4(0, 0, 0, 0);
        if (row < NN) {
            const ushort* srcp = (c < 16) ? (abf + (long long)row * 128 + c * 8)
                                          : (xbf + (long long)row * 128 + (c - 16) * 8);
            v = *(const uint4*)srcp;
        }
        *(uint4*)(a_sh + r * 512 + ((c * 16) ^ ((r & 7) << 4))) = v;
    }
    __syncthreads();

    int w = tid >> 6, l = tid & 63;
    int l15 = l & 15, kg = l >> 4;
    int lrow = 16 * w + l15;
    f32x4 acc[8];
#pragma unroll
    for (int n = 0; n < 8; ++n) {
        float b = bias[16 * n + l15];
        acc[n] = (f32x4){b, b, b, b};
    }
#pragma unroll
    for (int ks = 0; ks < 8; ++ks) {
        short8 af = *(const short8*)(a_sh + lrow * 512 + ((ks * 64 + kg * 16) ^ ((lrow & 7) << 4)));
        const short8* bp = ((const short8*)wp) + (ks * 8) * 64 + l;
#pragma unroll
        for (int n = 0; n < 8; ++n)
            acc[n] = __builtin_amdgcn_mfma_f32_16x16x32_bf16(af, bp[n * 64], acc[n], 0, 0, 0);
    }
#pragma unroll
    for (int n = 0; n < 8; ++n) {
        int col = 16 * n + l15;
#pragma unroll
        for (int r = 0; r < 4; ++r) {
            int row = row0 + 16 * w + kg * 4 + r;
            if (row < NN) hbf[(long long)row * CC + col] = f2bf(fmaxf(acc[n][r], 0.f));
        }
    }
}

// ---------------- MFMA layer2 + fused classifier ----------------
__global__ __launch_bounds__(256) void k_layer2_cls(
    const ushort* __restrict__ abf, const ushort* __restrict__ xbf,
    const ushort* __restrict__ wp2, const float* __restrict__ b2,
    const ushort* __restrict__ wpc, const float* __restrict__ bc,
    float* __restrict__ h2f, float* __restrict__ logits) {
    __shared__ uint4 a_sh4[2048];  // 32KB
    char* a_sh = (char*)a_sh4;
    int row0 = blockIdx.x * 64;
    int tid = threadIdx.x;
#pragma unroll
    for (int it = 0; it < 8; ++it) {
        int idx = tid + it * 256;
        int r = idx >> 5, c = idx & 31;
        int row = row0 + r;
        uint4 v = make_uint4(0, 0, 0, 0);
        if (row < NN) {
            const ushort* srcp = (c < 16) ? (abf + (long long)row * 128 + c * 8)
                                          : (xbf + (long long)row * 128 + (c - 16) * 8);
            v = *(const uint4*)srcp;
        }
        *(uint4*)(a_sh + r * 512 + ((c * 16) ^ ((r & 7) << 4))) = v;
    }
    __syncthreads();

    int w = tid >> 6, l = tid & 63;
    int l15 = l & 15, kg = l >> 4;
    int lrow = 16 * w + l15;
    f32x4 acc[8];
#pragma unroll
    for (int n = 0; n < 8; ++n) {
        float b = b2[16 * n + l15];
        acc[n] = (f32x4){b, b, b, b};
    }
#pragma unroll
    for (int ks = 0; ks < 8; ++ks) {
        short8 af = *(const short8*)(a_sh + lrow * 512 + ((ks * 64 + kg * 16) ^ ((lrow & 7) << 4)));
        const short8* bp = ((const short8*)wp2) + (ks * 8) * 64 + l;
#pragma unroll
        for (int n = 0; n < 8; ++n)
            acc[n] = __builtin_amdgcn_mfma_f32_16x16x32_bf16(af, bp[n * 64], acc[n], 0, 0, 0);
    }
    __syncthreads();

#pragma unroll
    for (int n = 0; n < 8; ++n) {
        int col = 16 * n + l15;
#pragma unroll
        for (int r = 0; r < 4; ++r) {
            int lr = 16 * w + kg * 4 + r;
            int row = row0 + lr;
            float v = fmaxf(acc[n][r], 0.f);
            if (row < NN) h2f[(long long)row * CC + col] = v;
            *(ushort*)(a_sh + lr * 256 + ((col * 2) ^ ((lr & 7) << 4))) = f2bf(v);
        }
    }
    __syncthreads();

    f32x4 acc2[4];
#pragma unroll
    for (int n = 0; n < 4; ++n) {
        float b = bc[16 * n + l15];
        acc2[n] = (f32x4){b, b, b, b};
    }
#pragma unroll
    for (int ks = 0; ks < 4; ++ks) {
        short8 af = *(const short8*)(a_sh + lrow * 256 + ((ks * 64 + kg * 16) ^ ((lrow & 7) << 4)));
        const short8* bp = ((const short8*)wpc) + (ks * 4) * 64 + l;
#pragma unroll
        for (int n = 0; n < 4; ++n)
            acc2[n] = __builtin_amdgcn_mfma_f32_16x16x32_bf16(af, bp[n * 64], acc2[n], 0, 0, 0);
    }
#pragma unroll
    for (int n = 0; n < 4; ++n) {
        int col = 16 * n + l15;
#pragma unroll
        for (int r = 0; r < 4; ++r) {
            int row = row0 + 16 * w + kg * 4 + r;
            if (row < NN) logits[(long long)row * OC + col] = acc2[n][r];
        }
    }
}

extern "C" void kernel_launch(void* const* d_in, const int* in_sizes, int n_in,
                              void* d_out, int out_size, void* d_ws, size_t ws_size,
                              hipStream_t stream) {
    const float* x_doc = (const float*)d_in[0];
    const int* ei = (const int*)d_in[2];
    const float* W1l = (const float*)d_in[4];
    const float* b1  = (const float*)d_in[5];
    const float* W1r = (const float*)d_in[6];
    const float* W2l = (const float*)d_in[7];
    const float* b2  = (const float*)d_in[8];
    const float* W2r = (const float*)d_in[9];
    const float* Wc  = (const float*)d_in[10];
    const float* bc  = (const float*)d_in[11];

    const int* src = ei;
    const int* dst = ei + EE;

    // workspace layout
    ushort* x_bf  = (ushort*)d_ws;                   // NN*CC
    ushort* aggr  = x_bf + (long long)NN * CC;       // NN*CC
    ushort* h1_bf = aggr + (long long)NN * CC;       // NN*CC
    ushort* wp1   = h1_bf + (long long)NN * CC;      // 32768
    ushort* wp2   = wp1 + 32768;                     // 32768
    ushort* wpc   = wp2 + 32768;                     // 8192
    int* gcnt     = (int*)(wpc + 8192);              // 256
    int* offs     = gcnt + 256;                      // NN (pad to 50176)
    int* offe     = offs + 50176;                    // NN (pad to 50176)
    int* ssrc     = offe + 50176;                    // NBKT*CAP
    uint* binned  = (uint*)(ssrc + NBKT * CAP);      // NBKT*CAP

    float* logits = (float*)d_out;                   // NN*OC
    float* h2f    = logits + (long long)NN * OC;     // NN*CC

    // CSR build: single-pass binning into padded segments + in-bucket sort
    hipMemsetAsync(gcnt, 0, 256 * sizeof(int), stream);
    k_bin<<<NBIN_BLK, 256, 0, stream>>>(src, dst, gcnt, binned);
    k_fine<<<NBKT, 256, 0, stream>>>(gcnt, binned, offs, offe, ssrc);

    // fused convert + weight packs
    k_prep<<<6286, 256, 0, stream>>>(x_doc, x_bf, W1l, W1r, wp1, W2l, W2r, wp2, Wc, wpc);

    // layer 1
    k_gather_bf<<<(NN + 15) / 16, 256, 0, stream>>>(offs, offe, ssrc, x_bf, aggr);
    k_layer_mfma<<<(NN + 63) / 64, 256, 0, stream>>>(aggr, x_bf, wp1, b1, h1_bf);

    // layer 2 + classifier
    k_gather_bf<<<(NN + 15) / 16, 256, 0, stream>>>(offs, offe, ssrc, h1_bf, aggr);
    k_layer2_cls<<<(NN + 63) / 64, 256, 0, stream>>>(aggr, h1_bf, wp2, b2, wpc, bc, h2f, logits);
}

// Round 7
// 128.470 us; speedup vs baseline: 23.5061x; 1.0736x over previous
//
#include <hip/hip_runtime.h>

#define NN 50000
#define CC 128
#define OC 64
#define EE 800000
#define NBKT 196      // buckets of 256 nodes
#define CAP 8192      // padded per-bucket capacity (mean 4096, sigma 64)
#define CHUNK 4096
#define NBIN_BLK 196  // ceil(EE/CHUNK)

typedef __attribute__((ext_vector_type(8))) short short8;
typedef __attribute__((ext_vector_type(4))) float f32x4;

__device__ __forceinline__ float bflo(uint v) { return __uint_as_float(v << 16); }
__device__ __forceinline__ float bfhi(uint v) { return __uint_as_float(v & 0xffff0000u); }
__device__ __forceinline__ ushort f2bf(float x) {
    uint u = __float_as_uint(x);
    return (ushort)((u + 0x7fffu + ((u >> 16) & 1u)) >> 16);
}

// ---------------- binning: one pass, padded bucket segments ----------------
__global__ __launch_bounds__(256) void k_bin(const int* __restrict__ src,
                                             const int* __restrict__ dst,
                                             int* __restrict__ gcnt,
                                             uint* __restrict__ binned) {
    __shared__ int h[256];
    __shared__ int gb[256];
    __shared__ int cur[256];
    int tid = threadIdx.x;
    h[tid] = 0;
    __syncthreads();
    int e0 = blockIdx.x * CHUNK;
    for (int i = tid; i < CHUNK; i += 256) {
        int e = e0 + i;
        if (e < EE) atomicAdd(&h[dst[e] >> 8], 1);
    }
    __syncthreads();
    if (tid < NBKT) {
        gb[tid] = h[tid] ? (tid * CAP + atomicAdd(&gcnt[tid], h[tid])) : 0;
        cur[tid] = 0;
    }
    __syncthreads();
    for (int i = tid; i < CHUNK; i += 256) {
        int e = e0 + i;
        if (e < EE) {
            int d = dst[e];
            int b = d >> 8;
            int r = atomicAdd(&cur[b], 1);
            binned[gb[b] + r] = ((uint)(d & 255) << 16) | (uint)src[e];
        }
    }
}

// ---------------- fine sort within bucket -> per-node [start,end) ----------------
__global__ __launch_bounds__(256) void k_fine(const int* __restrict__ gcnt,
                                              const uint* __restrict__ binned,
                                              int* __restrict__ offs,
                                              int* __restrict__ offe,
                                              int* __restrict__ ssrc) {
    __shared__ int hist[256];
    __shared__ int sc[256];
    __shared__ int curs[256];
    int b = blockIdx.x, tid = threadIdx.x;
    int s = b * CAP, cnt = gcnt[b];
    hist[tid] = 0;
    __syncthreads();
    for (int i = tid; i < cnt; i += 256) atomicAdd(&hist[binned[s + i] >> 16], 1);
    __syncthreads();
    int v = hist[tid];
    sc[tid] = v;
    __syncthreads();
    for (int d = 1; d < 256; d <<= 1) {
        int t = (tid >= d) ? sc[tid - d] : 0;
        __syncthreads();
        sc[tid] += t;
        __syncthreads();
    }
    int excl = sc[tid] - v;
    int idx = b * 256 + tid;
    if (idx < NN) { offs[idx] = s + excl; offe[idx] = s + excl + v; }
    curs[tid] = excl;
    __syncthreads();
    for (int i = tid; i < cnt; i += 256) {
        uint p = binned[s + i];
        int r = atomicAdd(&curs[p >> 16], 1);
        ssrc[s + r] = (int)(p & 0xffffu);
    }
}

// ---------------- fused prep: gcnt zero + x->bf16 convert + weight packs ----------------
__device__ __forceinline__ void packw_body(const float* __restrict__ Wl,
                                           const float* __restrict__ Wr,
                                           ushort* __restrict__ wp, int t) {
    int l = t & 63, n = (t >> 6) & 7, ks = t >> 9;
    int kg = l >> 4, col = 16 * n + (l & 15);
    uint out[4];
#pragma unroll
    for (int jj = 0; jj < 4; ++jj) {
        int k = 32 * ks + 8 * kg + 2 * jj;
        float v0 = (k < 128) ? Wl[k * 128 + col] : Wr[(k - 128) * 128 + col];
        float v1 = (k + 1 < 128) ? Wl[(k + 1) * 128 + col] : Wr[(k + 1 - 128) * 128 + col];
        out[jj] = (uint)f2bf(v0) | ((uint)f2bf(v1) << 16);
    }
    *(uint4*)(wp + (long long)t * 8) = make_uint4(out[0], out[1], out[2], out[3]);
}

__global__ __launch_bounds__(256) void k_prep(
    const float* __restrict__ x, ushort* __restrict__ xb,
    const float* __restrict__ W1l, const float* __restrict__ W1r, ushort* __restrict__ wp1,
    const float* __restrict__ W2l, const float* __restrict__ W2r, ushort* __restrict__ wp2,
    const float* __restrict__ Wc, ushort* __restrict__ wpc,
    int* __restrict__ gcnt) {
    int b = blockIdx.x, tid = threadIdx.x;
    if (b < 6250) {
        int i = b * 256 + tid;  // NN*CC/4 = 1,600,000 exactly
        float4 v = ((const float4*)x)[i];
        ushort4 u;
        u.x = f2bf(v.x); u.y = f2bf(v.y); u.z = f2bf(v.z); u.w = f2bf(v.w);
        ((ushort4*)xb)[i] = u;
    } else if (b < 6266) {
        packw_body(W1l, W1r, wp1, (b - 6250) * 256 + tid);
    } else if (b < 6282) {
        packw_body(W2l, W2r, wp2, (b - 6266) * 256 + tid);
    } else if (b < 6286) {
        int t = (b - 6282) * 256 + tid;  // < 1024
        int l = t & 63, n = (t >> 6) & 3, ks = t >> 8;
        int kg = l >> 4, col = 16 * n + (l & 15);
        uint out[4];
#pragma unroll
        for (int jj = 0; jj < 4; ++jj) {
            int k = 32 * ks + 8 * kg + 2 * jj;
            out[jj] = (uint)f2bf(Wc[k * 64 + col]) | ((uint)f2bf(Wc[(k + 1) * 64 + col]) << 16);
        }
        *(uint4*)(wpc + (long long)t * 8) = make_uint4(out[0], out[1], out[2], out[3]);
    } else {
        gcnt[tid] = 0;  // b == 6286
    }
}

// ---------------- fused gather + MFMA layer ----------------
// Gathers the block's 64 aggr rows directly into LDS (16-lane group per node,
// 4 nodes/group, 4-deep ILP), stages self rows, then MFMA.
__device__ __forceinline__ void gather_stage(
    const int* __restrict__ offs, const int* __restrict__ offe,
    const int* __restrict__ ssrc, const ushort* __restrict__ xbf,
    char* a_sh, int row0, int tid) {
    int grp = tid >> 4, l15 = tid & 15;
    // Phase B: gather neighbor-mean rows into left 256B half
#pragma unroll
    for (int rr = 0; rr < 4; ++rr) {
        int r = grp * 4 + rr;
        int node = row0 + r;
        int s0 = 0, s1 = 0;
        if (node < NN) { s0 = offs[node]; s1 = offe[node]; }
        float a0 = 0.f, a1 = 0.f, a2 = 0.f, a3 = 0.f;
        float a4 = 0.f, a5 = 0.f, a6 = 0.f, a7 = 0.f;
        int j = s0;
        for (; j + 3 < s1; j += 4) {
            int sa = ssrc[j], sb = ssrc[j + 1], sc = ssrc[j + 2], sd = ssrc[j + 3];
            uint4 va = ((const uint4*)(xbf + (long long)sa * CC))[l15];
            uint4 vb = ((const uint4*)(xbf + (long long)sb * CC))[l15];
            uint4 vc = ((const uint4*)(xbf + (long long)sc * CC))[l15];
            uint4 vd = ((const uint4*)(xbf + (long long)sd * CC))[l15];
            a0 += bflo(va.x) + bflo(vb.x) + bflo(vc.x) + bflo(vd.x);
            a1 += bfhi(va.x) + bfhi(vb.x) + bfhi(vc.x) + bfhi(vd.x);
            a2 += bflo(va.y) + bflo(vb.y) + bflo(vc.y) + bflo(vd.y);
            a3 += bfhi(va.y) + bfhi(vb.y) + bfhi(vc.y) + bfhi(vd.y);
            a4 += bflo(va.z) + bflo(vb.z) + bflo(vc.z) + bflo(vd.z);
            a5 += bfhi(va.z) + bfhi(vb.z) + bfhi(vc.z) + bfhi(vd.z);
            a6 += bflo(va.w) + bflo(vb.w) + bflo(vc.w) + bflo(vd.w);
            a7 += bfhi(va.w) + bfhi(vb.w) + bfhi(vc.w) + bfhi(vd.w);
        }
        if (j + 1 < s1) {
            int sa = ssrc[j], sb = ssrc[j + 1];
            uint4 va = ((const uint4*)(xbf + (long long)sa * CC))[l15];
            uint4 vb = ((const uint4*)(xbf + (long long)sb * CC))[l15];
            a0 += bflo(va.x) + bflo(vb.x); a1 += bfhi(va.x) + bfhi(vb.x);
            a2 += bflo(va.y) + bflo(vb.y); a3 += bfhi(va.y) + bfhi(vb.y);
            a4 += bflo(va.z) + bflo(vb.z); a5 += bfhi(va.z) + bfhi(vb.z);
            a6 += bflo(va.w) + bflo(vb.w); a7 += bfhi(va.w) + bfhi(vb.w);
            j += 2;
        }
        if (j < s1) {
            int sa = ssrc[j];
            uint4 va = ((const uint4*)(xbf + (long long)sa * CC))[l15];
            a0 += bflo(va.x); a1 += bfhi(va.x);
            a2 += bflo(va.y); a3 += bfhi(va.y);
            a4 += bflo(va.z); a5 += bfhi(va.z);
            a6 += bflo(va.w); a7 += bfhi(va.w);
        }
        float dinv = 1.0f / fmaxf((float)(s1 - s0), 1.0f);
        uint4 o;
        o.x = (uint)f2bf(a0 * dinv) | ((uint)f2bf(a1 * dinv) << 16);
        o.y = (uint)f2bf(a2 * dinv) | ((uint)f2bf(a3 * dinv) << 16);
        o.z = (uint)f2bf(a4 * dinv) | ((uint)f2bf(a5 * dinv) << 16);
        o.w = (uint)f2bf(a6 * dinv) | ((uint)f2bf(a7 * dinv) << 16);
        *(uint4*)(a_sh + r * 512 + ((l15 * 16) ^ ((r & 7) << 4))) = o;
    }
    // Phase A: stage self rows into right 256B half (linear loads)
#pragma unroll
    for (int it = 0; it < 4; ++it) {
        int idx = tid + it * 256;
        int r = idx >> 4, c = idx & 15;
        int row = row0 + r;
        uint4 v = make_uint4(0, 0, 0, 0);
        if (row < NN) v = ((const uint4*)(xbf + (long long)row * CC))[c];
        *(uint4*)(a_sh + r * 512 + ((256 + c * 16) ^ ((r & 7) << 4))) = v;
    }
}

__global__ __launch_bounds__(256) void k_fused_layer(
    const int* __restrict__ offs, const int* __restrict__ offe,
    const int* __restrict__ ssrc, const ushort* __restrict__ xbf,
    const ushort* __restrict__ wp, const float* __restrict__ bias,
    ushort* __restrict__ hbf) {
    __shared__ uint4 a_sh4[2048];  // 32KB
    char* a_sh = (char*)a_sh4;
    int row0 = blockIdx.x * 64;
    int tid = threadIdx.x;
    gather_stage(offs, offe, ssrc, xbf, a_sh, row0, tid);
    __syncthreads();

    int w = tid >> 6, l = tid & 63;
    int l15 = l & 15, kg = l >> 4;
    int lrow = 16 * w + l15;
    f32x4 acc[8];
#pragma unroll
    for (int n = 0; n < 8; ++n) {
        float b = bias[16 * n + l15];
        acc[n] = (f32x4){b, b, b, b};
    }
#pragma unroll
    for (int ks = 0; ks < 8; ++ks) {
        short8 af = *(const short8*)(a_sh + lrow * 512 + ((ks * 64 + kg * 16) ^ ((lrow & 7) << 4)));
        const short8* bp = ((const short8*)wp) + (ks * 8) * 64 + l;
#pragma unroll
        for (int n = 0; n < 8; ++n)
            acc[n] = __builtin_amdgcn_mfma_f32_16x16x32_bf16(af, bp[n * 64], acc[n], 0, 0, 0);
    }
#pragma unroll
    for (int n = 0; n < 8; ++n) {
        int col = 16 * n + l15;
#pragma unroll
        for (int r = 0; r < 4; ++r) {
            int row = row0 + 16 * w + kg * 4 + r;
            if (row < NN) hbf[(long long)row * CC + col] = f2bf(fmaxf(acc[n][r], 0.f));
        }
    }
}

// ---------------- fused gather + MFMA layer2 + classifier ----------------
__global__ __launch_bounds__(256) void k_fused_layer2_cls(
    const int* __restrict__ offs, const int* __restrict__ offe,
    const int* __restrict__ ssrc, const ushort* __restrict__ xbf,
    const ushort* __restrict__ wp2, const float* __restrict__ b2,
    const ushort* __restrict__ wpc, const float* __restrict__ bc,
    float* __restrict__ h2f, float* __restrict__ logits) {
    __shared__ uint4 a_sh4[2048];  // 32KB
    char* a_sh = (char*)a_sh4;
    int row0 = blockIdx.x * 64;
    int tid = threadIdx.x;
    gather_stage(offs, offe, ssrc, xbf, a_sh, row0, tid);
    __syncthreads();

    int w = tid >> 6, l = tid & 63;
    int l15 = l & 15, kg = l >> 4;
    int lrow = 16 * w + l15;
    f32x4 acc[8];
#pragma unroll
    for (int n = 0; n < 8; ++n) {
        float b = b2[16 * n + l15];
        acc[n] = (f32x4){b, b, b, b};
    }
#pragma unroll
    for (int ks = 0; ks < 8; ++ks) {
        short8 af = *(const short8*)(a_sh + lrow * 512 + ((ks * 64 + kg * 16) ^ ((lrow & 7) << 4)));
        const short8* bp = ((const short8*)wp2) + (ks * 8) * 64 + l;
#pragma unroll
        for (int n = 0; n < 8; ++n)
            acc[n] = __builtin_amdgcn_mfma_f32_16x16x32_bf16(af, bp[n * 64], acc[n], 0, 0, 0);
    }
    __syncthreads();

    // epilogue: relu -> h2 f32 (global) + bf16 into cls LDS [64][128] swizzled
#pragma unroll
    for (int n = 0; n < 8; ++n) {
        int col = 16 * n + l15;
#pragma unroll
        for (int r = 0; r < 4; ++r) {
            int lr = 16 * w + kg * 4 + r;
            int row = row0 + lr;
            float v = fmaxf(acc[n][r], 0.f);
            if (row < NN) h2f[(long long)row * CC + col] = v;
            *(ushort*)(a_sh + lr * 256 + ((col * 2) ^ ((lr & 7) << 4))) = f2bf(v);
        }
    }
    __syncthreads();

    f32x4 acc2[4];
#pragma unroll
    for (int n = 0; n < 4; ++n) {
        float b = bc[16 * n + l15];
        acc2[n] = (f32x4){b, b, b, b};
    }
#pragma unroll
    for (int ks = 0; ks < 4; ++ks) {
        short8 af = *(const short8*)(a_sh + lrow * 256 + ((ks * 64 + kg * 16) ^ ((lrow & 7) << 4)));
        const short8* bp = ((const short8*)wpc) + (ks * 4) * 64 + l;
#pragma unroll
        for (int n = 0; n < 4; ++n)
            acc2[n] = __builtin_amdgcn_mfma_f32_16x16x32_bf16(af, bp[n * 64], acc2[n], 0, 0, 0);
    }
#pragma unroll
    for (int n = 0; n < 4; ++n) {
        int col = 16 * n + l15;
#pragma unroll
        for (int r = 0; r < 4; ++r) {
            int row = row0 + 16 * w + kg * 4 + r;
            if (row < NN) logits[(long long)row * OC + col] = acc2[n][r];
        }
    }
}

extern "C" void kernel_launch(void* const* d_in, const int* in_sizes, int n_in,
                              void* d_out, int out_size, void* d_ws, size_t ws_size,
                              hipStream_t stream) {
    const float* x_doc = (const float*)d_in[0];
    const int* ei = (const int*)d_in[2];
    const float* W1l = (const float*)d_in[4];
    const float* b1  = (const float*)d_in[5];
    const float* W1r = (const float*)d_in[6];
    const float* W2l = (const float*)d_in[7];
    const float* b2  = (const float*)d_in[8];
    const float* W2r = (const float*)d_in[9];
    const float* Wc  = (const float*)d_in[10];
    const float* bc  = (const float*)d_in[11];

    const int* src = ei;
    const int* dst = ei + EE;

    // workspace layout
    ushort* x_bf  = (ushort*)d_ws;                   // NN*CC
    ushort* h1_bf = x_bf + (long long)NN * CC;       // NN*CC
    ushort* wp1   = h1_bf + (long long)NN * CC;      // 32768
    ushort* wp2   = wp1 + 32768;                     // 32768
    ushort* wpc   = wp2 + 32768;                     // 8192
    int* gcnt     = (int*)(wpc + 8192);              // 256
    int* offs     = gcnt + 256;                      // NN (pad to 50176)
    int* offe     = offs + 50176;                    // NN (pad to 50176)
    int* ssrc     = offe + 50176;                    // NBKT*CAP
    uint* binned  = (uint*)(ssrc + NBKT * CAP);      // NBKT*CAP

    float* logits = (float*)d_out;                   // NN*OC
    float* h2f    = logits + (long long)NN * OC;     // NN*CC

    // prep (also zeros gcnt) -> bin -> fine
    k_prep<<<6287, 256, 0, stream>>>(x_doc, x_bf, W1l, W1r, wp1, W2l, W2r, wp2,
                                     Wc, wpc, gcnt);
    k_bin<<<NBIN_BLK, 256, 0, stream>>>(src, dst, gcnt, binned);
    k_fine<<<NBKT, 256, 0, stream>>>(gcnt, binned, offs, offe, ssrc);

    // layer 1 (gather fused)
    k_fused_layer<<<(NN + 63) / 64, 256, 0, stream>>>(offs, offe, ssrc, x_bf, wp1, b1, h1_bf);

    // layer 2 + classifier (gather fused)
    k_fused_layer2_cls<<<(NN + 63) / 64, 256, 0, stream>>>(offs, offe, ssrc, h1_bf,
                                                           wp2, b2, wpc, bc, h2f, logits);
}